// Round 1
// baseline (4143.347 us; speedup 1.0000x reference)
//
#include <hip/hip_runtime.h>

// ---------------------------------------------------------------------------
// GCN encoder: 2-layer GCNConv (+ a parallel conv2 head), N=50000, E=1.6M, D=128.
// Round 1: correctness-first full-f32 pipeline. Aggregation via f32 atomics.
// ---------------------------------------------------------------------------

#define D 128

// deg[dst] += 1 per edge (f32 atomic; exact for counts < 2^24)
__global__ __launch_bounds__(256) void k_deg(const int* __restrict__ dst,
                                             float* __restrict__ deg, int E) {
  int i = blockIdx.x * 256 + threadIdx.x;
  if (i < E) atomicAdd(&deg[dst[i]], 1.0f);
}

// dinv = rsqrt(deg + 1)  (in place)
__global__ __launch_bounds__(256) void k_dinv(float* __restrict__ deg, int n) {
  int i = blockIdx.x * 256 + threadIdx.x;
  if (i < n) deg[i] = rsqrtf(deg[i] + 1.0f);
}

// C[i][j] = sum_k X[i][k] * W[j][k]   (X: [nrows][128], W: [128][128] row-major)
// 64 rows/block, 256 threads, 4x8 register blocking, W staged transposed in
// 32-wide k chunks.
__global__ __launch_bounds__(256) void k_gemm128(const float* __restrict__ X,
                                                 const float* __restrict__ W,
                                                 float* __restrict__ C, int nrows) {
  __shared__ float Xs[64][132];   // +4 pad: ty-groups land on 2 banks (free 2-way)
  __shared__ float Ws[32][128];   // transposed chunk: Ws[kk][j] = W[j][k0+kk]

  int tid  = threadIdx.x;
  int row0 = blockIdx.x * 64;

  // stage X tile (float4 global loads, scalar LDS stores into padded rows)
  for (int t = tid; t < 2048; t += 256) {
    int r  = t >> 5;
    int c4 = (t & 31) << 2;
    int gr = row0 + r;
    float4 v = make_float4(0.f, 0.f, 0.f, 0.f);
    if (gr < nrows) v = *(const float4*)(X + (size_t)gr * D + c4);
    Xs[r][c4 + 0] = v.x; Xs[r][c4 + 1] = v.y;
    Xs[r][c4 + 2] = v.z; Xs[r][c4 + 3] = v.w;
  }

  float acc[4][8];
#pragma unroll
  for (int i = 0; i < 4; ++i)
#pragma unroll
    for (int j = 0; j < 8; ++j) acc[i][j] = 0.f;

  int ty = tid >> 4, tx = tid & 15;
  int r0 = ty << 2, c0 = tx << 3;

  for (int k0 = 0; k0 < 128; k0 += 32) {
    // read W chunk to regs first (no LDS dependence yet)
    int j   = tid >> 1;
    int kkb = (tid & 1) << 4;
    const float4* wp = (const float4*)(W + j * D + k0 + kkb);
    float4 wa = wp[0], wb = wp[1], wc = wp[2], wd = wp[3];

    __syncthreads();   // previous iteration's reads (and Xs staging) done
    Ws[kkb +  0][j] = wa.x; Ws[kkb +  1][j] = wa.y; Ws[kkb +  2][j] = wa.z; Ws[kkb +  3][j] = wa.w;
    Ws[kkb +  4][j] = wb.x; Ws[kkb +  5][j] = wb.y; Ws[kkb +  6][j] = wb.z; Ws[kkb +  7][j] = wb.w;
    Ws[kkb +  8][j] = wc.x; Ws[kkb +  9][j] = wc.y; Ws[kkb + 10][j] = wc.z; Ws[kkb + 11][j] = wc.w;
    Ws[kkb + 12][j] = wd.x; Ws[kkb + 13][j] = wd.y; Ws[kkb + 14][j] = wd.z; Ws[kkb + 15][j] = wd.w;
    __syncthreads();   // Ws ready

#pragma unroll
    for (int kk = 0; kk < 32; ++kk) {
      float xi[4];
      xi[0] = Xs[r0 + 0][k0 + kk];
      xi[1] = Xs[r0 + 1][k0 + kk];
      xi[2] = Xs[r0 + 2][k0 + kk];
      xi[3] = Xs[r0 + 3][k0 + kk];
      float4 wv0 = *(const float4*)(&Ws[kk][c0]);
      float4 wv1 = *(const float4*)(&Ws[kk][c0 + 4]);
      float wf[8] = {wv0.x, wv0.y, wv0.z, wv0.w, wv1.x, wv1.y, wv1.z, wv1.w};
#pragma unroll
      for (int i = 0; i < 4; ++i)
#pragma unroll
        for (int jj = 0; jj < 8; ++jj) acc[i][jj] += xi[i] * wf[jj];
    }
  }

#pragma unroll
  for (int i = 0; i < 4; ++i) {
    int gr = row0 + r0 + i;
    if (gr < nrows) {
      float4 v0 = make_float4(acc[i][0], acc[i][1], acc[i][2], acc[i][3]);
      float4 v1 = make_float4(acc[i][4], acc[i][5], acc[i][6], acc[i][7]);
      *(float4*)(C + (size_t)gr * D + c0)     = v0;
      *(float4*)(C + (size_t)gr * D + c0 + 4) = v1;
    }
  }
}

// out[i][j] = H[i][j] * dinv[i]^2 + b[j]   (also serves as output-buffer init)
__global__ __launch_bounds__(256) void k_selfinit(const float* __restrict__ H,
                                                  const float* __restrict__ dinv,
                                                  const float* __restrict__ bias,
                                                  float* __restrict__ out, int n) {
  int i = blockIdx.x * 256 + threadIdx.x;   // over n*32 float4s
  if (i >= n * 32) return;
  int r  = i >> 5;
  int c4 = (i & 31) << 2;
  float di = dinv[r];
  float s  = di * di;
  float4 h = *(const float4*)(H + (size_t)r * D + c4);
  float4 b = *(const float4*)(bias + c4);
  float4 o;
  o.x = h.x * s + b.x; o.y = h.y * s + b.y;
  o.z = h.z * s + b.z; o.w = h.w * s + b.w;
  *(float4*)(out + (size_t)r * D + c4) = o;
}

// h = relu(h * mask)  in place, float4
__global__ __launch_bounds__(256) void k_relumask(float* __restrict__ h,
                                                  const float* __restrict__ mask, int n) {
  int i = blockIdx.x * 256 + threadIdx.x;   // over n*32 float4s
  if (i >= n * 32) return;
  float4 v = *(const float4*)(h + (size_t)i * 4);
  float4 m = *(const float4*)(mask + (size_t)i * 4);
  v.x = fmaxf(v.x * m.x, 0.f);
  v.y = fmaxf(v.y * m.y, 0.f);
  v.z = fmaxf(v.z * m.z, 0.f);
  v.w = fmaxf(v.w * m.w, 0.f);
  *(float4*)(h + (size_t)i * 4) = v;
}

// per edge: out[dst] += H[src] * dinv[src]*dinv[dst]; one wave per edge,
// lane l owns cols 2l, 2l+1 (float2 gather + 2 f32 atomics)
__global__ __launch_bounds__(256) void k_agg(const float* __restrict__ H,
                                             const int* __restrict__ src,
                                             const int* __restrict__ dst,
                                             const float* __restrict__ dinv,
                                             float* __restrict__ out, int E) {
  int gid  = blockIdx.x * 256 + threadIdx.x;
  int wave = gid >> 6;
  int lane = threadIdx.x & 63;
  int nw   = (gridDim.x * 256) >> 6;
  for (int e = wave; e < E; e += nw) {
    int s = src[e], d = dst[e];
    float nrm = dinv[s] * dinv[d];
    float2 v  = ((const float2*)(H + (size_t)s * D))[lane];
    float* op = out + (size_t)d * D + lane * 2;
    atomicAdd(op,     v.x * nrm);
    atomicAdd(op + 1, v.y * nrm);
  }
}

extern "C" void kernel_launch(void* const* d_in, const int* in_sizes, int n_in,
                              void* d_out, int out_size, void* d_ws, size_t ws_size,
                              hipStream_t stream) {
  const float* x    = (const float*)d_in[0];
  const int*   ei   = (const int*)d_in[1];
  const float* mask = (const float*)d_in[2];
  const float* W0   = (const float*)d_in[3];
  const float* b0   = (const float*)d_in[4];
  const float* W1   = (const float*)d_in[5];
  const float* b1   = (const float*)d_in[6];
  const float* W2   = (const float*)d_in[7];
  const float* b2   = (const float*)d_in[8];

  const int N = in_sizes[0] / D;
  const int E = in_sizes[1] / 2;
  const int* srcv = ei;
  const int* dstv = ei + E;

  float* out   = (float*)d_out;
  float* outA  = out;                      // x_
  float* outB  = out + (size_t)N * D;      // x2

  size_t featBytes = (size_t)N * D * sizeof(float);
  float* dinv = (float*)d_ws;
  float* A    = (float*)((char*)d_ws + 0x40000);
  float* B    = (float*)((char*)d_ws + 0x40000 + featBytes);

  const int gElem = (N * 32 + 255) / 256;       // float4-elementwise grids
  const int gGemm = (N + 63) / 64;
  const int gEdge = (E + 255) / 256;

  // degrees -> dinv
  hipMemsetAsync(dinv, 0, (size_t)N * sizeof(float), stream);
  k_deg<<<gEdge, 256, 0, stream>>>(dstv, dinv, E);
  k_dinv<<<(N + 255) / 256, 256, 0, stream>>>(dinv, N);

  // layer 0: h0 = x @ W0^T ; out0 = agg(h0) + h0*dinv^2 + b0 ; h = relu(out0*mask)
  k_gemm128<<<gGemm, 256, 0, stream>>>(x, W0, A, N);
  k_selfinit<<<gElem, 256, 0, stream>>>(A, dinv, b0, B, N);
  k_agg<<<4096, 256, 0, stream>>>(A, srcv, dstv, dinv, B, E);
  k_relumask<<<gElem, 256, 0, stream>>>(B, mask, N);

  // layer 1: x_ = agg(h @ W1^T) + ... + b1
  k_gemm128<<<gGemm, 256, 0, stream>>>(B, W1, A, N);
  k_selfinit<<<gElem, 256, 0, stream>>>(A, dinv, b1, outA, N);
  k_agg<<<4096, 256, 0, stream>>>(A, srcv, dstv, dinv, outA, E);

  // layer 2: x2 = agg(h @ W2^T) + ... + b2
  k_gemm128<<<gGemm, 256, 0, stream>>>(B, W2, A, N);
  k_selfinit<<<gElem, 256, 0, stream>>>(A, dinv, b2, outB, N);
  k_agg<<<4096, 256, 0, stream>>>(A, srcv, dstv, dinv, outB, E);
}

// Round 2
// 543.987 us; speedup vs baseline: 7.6166x; 7.6166x over previous
//
#include <hip/hip_runtime.h>

// ---------------------------------------------------------------------------
// GCN encoder, N=50000, E=1.6M, D=128.
// Round 2: commute agg past GEMMs (3 aggs -> 2), CSR counting-sort
// aggregation (no float atomics), fused bias / dropout-relu epilogues.
// ---------------------------------------------------------------------------

#define D 128

// ---------------- CSR build ----------------

__global__ __launch_bounds__(256) void k_hist(const int* __restrict__ dst,
                                              int* __restrict__ cnt, int E) {
  int i = blockIdx.x * 256 + threadIdx.x;
  if (i < E) atomicAdd(&cnt[dst[i]], 1);
}

__global__ __launch_bounds__(256) void k_dinv(const int* __restrict__ cnt,
                                              float* __restrict__ dinv, int n) {
  int i = blockIdx.x * 256 + threadIdx.x;
  if (i < n) dinv[i] = rsqrtf((float)cnt[i] + 1.0f);
}

__global__ __launch_bounds__(256) void k_scan1(const int* __restrict__ cnt,
                                               int* __restrict__ csum, int n) {
  __shared__ int sm[256];
  int b = blockIdx.x, t = threadIdx.x;
  int base = b * 1024, s = 0;
  for (int i = t; i < 1024; i += 256) {
    int idx = base + i;
    s += (idx < n) ? cnt[idx] : 0;
  }
  sm[t] = s;
  __syncthreads();
  for (int off = 128; off > 0; off >>= 1) {
    if (t < off) sm[t] += sm[t + off];
    __syncthreads();
  }
  if (t == 0) csum[b] = sm[0];
}

__global__ __launch_bounds__(64) void k_scan2(int* __restrict__ csum, int nch) {
  int lane = threadIdx.x & 63;
  if (nch <= 64) {
    int orig = (lane < nch) ? csum[lane] : 0;
    int v = orig;
    for (int off = 1; off < 64; off <<= 1) {
      int y = __shfl_up(v, off);
      if (lane >= off) v += y;
    }
    if (lane < nch) csum[lane] = v - orig;
  } else if (lane == 0) {
    int run = 0;
    for (int i = 0; i < nch; ++i) { int v = csum[i]; csum[i] = run; run += v; }
  }
}

__global__ __launch_bounds__(256) void k_scan3(const int* __restrict__ cnt,
                                               const int* __restrict__ csum,
                                               int* __restrict__ rowptr,
                                               int* __restrict__ cursor,
                                               int n, int E) {
  __shared__ int sm[256];
  int b = blockIdx.x, t = threadIdx.x;
  int base = b * 1024;
  int v[4], loc = 0;
#pragma unroll
  for (int k = 0; k < 4; ++k) {
    int idx = base + t * 4 + k;
    v[k] = (idx < n) ? cnt[idx] : 0;
    loc += v[k];
  }
  sm[t] = loc;
  __syncthreads();
  for (int off = 1; off < 256; off <<= 1) {
    int y = (t >= off) ? sm[t - off] : 0;
    __syncthreads();
    sm[t] += y;
    __syncthreads();
  }
  int run = csum[b] + sm[t] - loc;
#pragma unroll
  for (int k = 0; k < 4; ++k) {
    int idx = base + t * 4 + k;
    if (idx < n) { rowptr[idx] = run; cursor[idx] = run; run += v[k]; }
  }
  if (b == 0 && t == 0) rowptr[n] = E;
}

__global__ __launch_bounds__(256) void k_scatter(const int* __restrict__ src,
                                                 const int* __restrict__ dst,
                                                 int* __restrict__ cursor,
                                                 int* __restrict__ srcSorted, int E) {
  int i = blockIdx.x * 256 + threadIdx.x;
  if (i < E) {
    int d = dst[i];
    int p = atomicAdd(&cursor[d], 1);
    srcSorted[p] = src[i];
  }
}

// ---------------- aggregation (CSR, wave per node) ----------------

__global__ __launch_bounds__(256) void k_aggcsr(const float* __restrict__ X,
                                                const int* __restrict__ srcSorted,
                                                const int* __restrict__ rowptr,
                                                const float* __restrict__ dinv,
                                                float* __restrict__ out, int n) {
  int wave = (blockIdx.x * 256 + threadIdx.x) >> 6;
  int lane = threadIdx.x & 63;
  if (wave >= n) return;
  int beg = rowptr[wave], end = rowptr[wave + 1];
  float ax = 0.f, ay = 0.f;
  int j = beg;
  for (; j + 3 < end; j += 4) {
    int s0 = srcSorted[j], s1 = srcSorted[j + 1];
    int s2 = srcSorted[j + 2], s3 = srcSorted[j + 3];
    float w0 = dinv[s0], w1 = dinv[s1], w2 = dinv[s2], w3 = dinv[s3];
    float2 v0 = ((const float2*)(X + (size_t)s0 * D))[lane];
    float2 v1 = ((const float2*)(X + (size_t)s1 * D))[lane];
    float2 v2 = ((const float2*)(X + (size_t)s2 * D))[lane];
    float2 v3 = ((const float2*)(X + (size_t)s3 * D))[lane];
    ax += v0.x * w0 + v1.x * w1 + v2.x * w2 + v3.x * w3;
    ay += v0.y * w0 + v1.y * w1 + v2.y * w2 + v3.y * w3;
  }
  for (; j < end; ++j) {
    int s = srcSorted[j];
    float w = dinv[s];
    float2 v = ((const float2*)(X + (size_t)s * D))[lane];
    ax += v.x * w;
    ay += v.y * w;
  }
  float dn = dinv[wave];
  float2 sv = ((const float2*)(X + (size_t)wave * D))[lane];
  float2 o;
  o.x = ax * dn + sv.x * dn * dn;
  o.y = ay * dn + sv.y * dn * dn;
  ((float2*)(out + (size_t)wave * D))[lane] = o;
}

// ---------------- atomic fallback helpers ----------------

__global__ __launch_bounds__(256) void k_deg_f(const int* __restrict__ dst,
                                               float* __restrict__ deg, int E) {
  int i = blockIdx.x * 256 + threadIdx.x;
  if (i < E) atomicAdd(&deg[dst[i]], 1.0f);
}

__global__ __launch_bounds__(256) void k_dinv_f(float* __restrict__ deg, int n) {
  int i = blockIdx.x * 256 + threadIdx.x;
  if (i < n) deg[i] = rsqrtf(deg[i] + 1.0f);
}

__global__ __launch_bounds__(256) void k_selfmul(const float* __restrict__ X,
                                                 const float* __restrict__ dinv,
                                                 float* __restrict__ out, int n) {
  int i = blockIdx.x * 256 + threadIdx.x;
  if (i >= n * 32) return;
  int r = i >> 5, c4 = (i & 31) << 2;
  float di = dinv[r];
  float s = di * di;
  float4 h = *(const float4*)(X + (size_t)r * D + c4);
  h.x *= s; h.y *= s; h.z *= s; h.w *= s;
  *(float4*)(out + (size_t)r * D + c4) = h;
}

__global__ __launch_bounds__(256) void k_aggatomic(const float* __restrict__ X,
                                                   const int* __restrict__ src,
                                                   const int* __restrict__ dst,
                                                   const float* __restrict__ dinv,
                                                   float* __restrict__ out, int E) {
  int gid = blockIdx.x * 256 + threadIdx.x;
  int wave = gid >> 6;
  int lane = threadIdx.x & 63;
  int nw = (gridDim.x * 256) >> 6;
  for (int e = wave; e < E; e += nw) {
    int s = src[e], d = dst[e];
    float nrm = dinv[s] * dinv[d];
    float2 v = ((const float2*)(X + (size_t)s * D))[lane];
    float* op = out + (size_t)d * D + lane * 2;
    atomicAdd(op, v.x * nrm);
    atomicAdd(op + 1, v.y * nrm);
  }
}

// ---------------- GEMM: C = X @ W^T + b, optional relu(C*mask) ----------------

__global__ __launch_bounds__(256) void k_gemm128(const float* __restrict__ X,
                                                 const float* __restrict__ W,
                                                 const float* __restrict__ bias,
                                                 const float* __restrict__ mask,
                                                 float* __restrict__ C, int nrows) {
  __shared__ float Xs[64][132];
  __shared__ float Ws[32][128];

  int tid = threadIdx.x;
  int row0 = blockIdx.x * 64;

  for (int t = tid; t < 2048; t += 256) {
    int r = t >> 5;
    int c4 = (t & 31) << 2;
    int gr = row0 + r;
    float4 v = make_float4(0.f, 0.f, 0.f, 0.f);
    if (gr < nrows) v = *(const float4*)(X + (size_t)gr * D + c4);
    Xs[r][c4 + 0] = v.x; Xs[r][c4 + 1] = v.y;
    Xs[r][c4 + 2] = v.z; Xs[r][c4 + 3] = v.w;
  }

  float acc[4][8];
#pragma unroll
  for (int i = 0; i < 4; ++i)
#pragma unroll
    for (int j = 0; j < 8; ++j) acc[i][j] = 0.f;

  int ty = tid >> 4, tx = tid & 15;
  int r0 = ty << 2, c0 = tx << 3;

  for (int k0 = 0; k0 < 128; k0 += 32) {
    int j = tid >> 1;
    int kkb = (tid & 1) << 4;
    const float4* wp = (const float4*)(W + j * D + k0 + kkb);
    float4 wa = wp[0], wb = wp[1], wc = wp[2], wd = wp[3];

    __syncthreads();
    Ws[kkb +  0][j] = wa.x; Ws[kkb +  1][j] = wa.y; Ws[kkb +  2][j] = wa.z; Ws[kkb +  3][j] = wa.w;
    Ws[kkb +  4][j] = wb.x; Ws[kkb +  5][j] = wb.y; Ws[kkb +  6][j] = wb.z; Ws[kkb +  7][j] = wb.w;
    Ws[kkb +  8][j] = wc.x; Ws[kkb +  9][j] = wc.y; Ws[kkb + 10][j] = wc.z; Ws[kkb + 11][j] = wc.w;
    Ws[kkb + 12][j] = wd.x; Ws[kkb + 13][j] = wd.y; Ws[kkb + 14][j] = wd.z; Ws[kkb + 15][j] = wd.w;
    __syncthreads();

#pragma unroll
    for (int kk = 0; kk < 32; ++kk) {
      float xi[4];
      xi[0] = Xs[r0 + 0][k0 + kk];
      xi[1] = Xs[r0 + 1][k0 + kk];
      xi[2] = Xs[r0 + 2][k0 + kk];
      xi[3] = Xs[r0 + 3][k0 + kk];
      float4 wv0 = *(const float4*)(&Ws[kk][c0]);
      float4 wv1 = *(const float4*)(&Ws[kk][c0 + 4]);
      float wf[8] = {wv0.x, wv0.y, wv0.z, wv0.w, wv1.x, wv1.y, wv1.z, wv1.w};
#pragma unroll
      for (int i = 0; i < 4; ++i)
#pragma unroll
        for (int jj = 0; jj < 8; ++jj) acc[i][jj] += xi[i] * wf[jj];
    }
  }

  float4 bv0 = *(const float4*)(bias + c0);
  float4 bv1 = *(const float4*)(bias + c0 + 4);

#pragma unroll
  for (int i = 0; i < 4; ++i) {
    int gr = row0 + r0 + i;
    if (gr < nrows) {
      float4 v0 = make_float4(acc[i][0] + bv0.x, acc[i][1] + bv0.y,
                              acc[i][2] + bv0.z, acc[i][3] + bv0.w);
      float4 v1 = make_float4(acc[i][4] + bv1.x, acc[i][5] + bv1.y,
                              acc[i][6] + bv1.z, acc[i][7] + bv1.w);
      if (mask) {
        float4 m0 = *(const float4*)(mask + (size_t)gr * D + c0);
        float4 m1 = *(const float4*)(mask + (size_t)gr * D + c0 + 4);
        v0.x = fmaxf(v0.x * m0.x, 0.f); v0.y = fmaxf(v0.y * m0.y, 0.f);
        v0.z = fmaxf(v0.z * m0.z, 0.f); v0.w = fmaxf(v0.w * m0.w, 0.f);
        v1.x = fmaxf(v1.x * m1.x, 0.f); v1.y = fmaxf(v1.y * m1.y, 0.f);
        v1.z = fmaxf(v1.z * m1.z, 0.f); v1.w = fmaxf(v1.w * m1.w, 0.f);
      }
      *(float4*)(C + (size_t)gr * D + c0)     = v0;
      *(float4*)(C + (size_t)gr * D + c0 + 4) = v1;
    }
  }
}

// ---------------- launch ----------------

extern "C" void kernel_launch(void* const* d_in, const int* in_sizes, int n_in,
                              void* d_out, int out_size, void* d_ws, size_t ws_size,
                              hipStream_t stream) {
  const float* x    = (const float*)d_in[0];
  const int*   ei   = (const int*)d_in[1];
  const float* mask = (const float*)d_in[2];
  const float* W0   = (const float*)d_in[3];
  const float* b0   = (const float*)d_in[4];
  const float* W1   = (const float*)d_in[5];
  const float* b1   = (const float*)d_in[6];
  const float* W2   = (const float*)d_in[7];
  const float* b2   = (const float*)d_in[8];

  const int N = in_sizes[0] / D;
  const int E = in_sizes[1] / 2;
  const int* srcv = ei;
  const int* dstv = ei + E;

  float* out  = (float*)d_out;
  float* outA = out;                    // x_
  float* outB = out + (size_t)N * D;    // x2

  const size_t featBytes = (size_t)N * D * sizeof(float);
  const int gElem  = (N * 32 + 255) / 256;
  const int gGemm  = (N + 63) / 64;
  const int gEdge  = (E + 255) / 256;
  const int gNode  = (N + 255) / 256;
  const int gWaveN = (N + 3) / 4;
  const int nch    = (N + 1023) / 1024;

  char* w = (char*)d_ws;
  int*   cnt       = (int*)(w);
  float* dinv      = (float*)(w + 0x40000);
  int*   rowptr    = (int*)(w + 0x80000);
  int*   cursor    = (int*)(w + 0xC0000);
  int*   csum      = (int*)(w + 0xC0000 + ((size_t)N + 64) * sizeof(int));
  int*   srcSorted = (int*)(w + 0x140000);
  float* bufA      = (float*)(w + 0x140000 + ((size_t)E + 65536) * sizeof(int));
  float* bufB      = (float*)((char*)bufA + featBytes);
  size_t need = (size_t)(((char*)bufB + featBytes) - w);

  if (ws_size >= need) {
    hipMemsetAsync(cnt, 0, (size_t)N * sizeof(int), stream);
    k_hist<<<gEdge, 256, 0, stream>>>(dstv, cnt, E);
    k_dinv<<<gNode, 256, 0, stream>>>(cnt, dinv, N);
    k_scan1<<<nch, 256, 0, stream>>>(cnt, csum, N);
    k_scan2<<<1, 64, 0, stream>>>(csum, nch);
    k_scan3<<<nch, 256, 0, stream>>>(cnt, csum, rowptr, cursor, N, E);
    k_scatter<<<gEdge, 256, 0, stream>>>(srcv, dstv, cursor, srcSorted, E);

    // layer 0: h = relu((agg(x) @ W0^T + b0) * mask)
    k_aggcsr<<<gWaveN, 256, 0, stream>>>(x, srcSorted, rowptr, dinv, bufA, N);
    k_gemm128<<<gGemm, 256, 0, stream>>>(bufA, W0, b0, mask, bufB, N);
    // layers 1+2 share g = agg(h)
    k_aggcsr<<<gWaveN, 256, 0, stream>>>(bufB, srcSorted, rowptr, dinv, bufA, N);
    k_gemm128<<<gGemm, 256, 0, stream>>>(bufA, W1, b1, nullptr, outA, N);
    k_gemm128<<<gGemm, 256, 0, stream>>>(bufA, W2, b2, nullptr, outB, N);
  } else {
    // atomic fallback, still commuted (2 aggs)
    float* fdinv = (float*)(w);
    float* fA    = (float*)(w + 0x40000);
    float* fB    = (float*)((char*)fA + featBytes);
    hipMemsetAsync(fdinv, 0, (size_t)N * sizeof(float), stream);
    k_deg_f<<<gEdge, 256, 0, stream>>>(dstv, fdinv, E);
    k_dinv_f<<<gNode, 256, 0, stream>>>(fdinv, N);
    k_selfmul<<<gElem, 256, 0, stream>>>(x, fdinv, fA, N);
    k_aggatomic<<<4096, 256, 0, stream>>>(x, srcv, dstv, fdinv, fA, E);
    k_gemm128<<<gGemm, 256, 0, stream>>>(fA, W0, b0, mask, fB, N);
    k_selfmul<<<gElem, 256, 0, stream>>>(fB, fdinv, fA, N);
    k_aggatomic<<<4096, 256, 0, stream>>>(fB, srcv, dstv, fdinv, fA, E);
    k_gemm128<<<gGemm, 256, 0, stream>>>(fA, W1, b1, nullptr, outA, N);
    k_gemm128<<<gGemm, 256, 0, stream>>>(fA, W2, b2, nullptr, outB, N);
  }
}

// Round 5
// 483.876 us; speedup vs baseline: 8.5628x; 1.1242x over previous
//
#include <hip/hip_runtime.h>

// ---------------------------------------------------------------------------
// GCN encoder, N=50000, E=1.6M, D=128.
// Round 5 (= round 3 resubmit after 2x infra failure): two-phase bucketed
// counting sort for CSR build (coalesced writes). Agg + GEMM unchanged.
// ---------------------------------------------------------------------------

#define D 128
#define BK_SHIFT 7            // 128 nodes per bucket
#define BK_NODES 128
#define NBMAX 512             // max buckets (N <= 65536)
#define BUFCAP 6144           // LDS staging capacity (edges) in k_bucketB
#define TILE_A 16384          // edges per block in k_bucketA

// ---------------- CSR build ----------------

__global__ __launch_bounds__(256) void k_hist(const int* __restrict__ dst,
                                              int* __restrict__ cnt, int E) {
  int i = blockIdx.x * 256 + threadIdx.x;
  if (i < E) atomicAdd(&cnt[dst[i]], 1);
}

__global__ __launch_bounds__(256) void k_dinv(const int* __restrict__ cnt,
                                              float* __restrict__ dinv, int n) {
  int i = blockIdx.x * 256 + threadIdx.x;
  if (i < n) dinv[i] = rsqrtf((float)cnt[i] + 1.0f);
}

__global__ __launch_bounds__(256) void k_scan1(const int* __restrict__ cnt,
                                               int* __restrict__ csum, int n) {
  __shared__ int sm[256];
  int b = blockIdx.x, t = threadIdx.x;
  int base = b * 1024, s = 0;
  for (int i = t; i < 1024; i += 256) {
    int idx = base + i;
    s += (idx < n) ? cnt[idx] : 0;
  }
  sm[t] = s;
  __syncthreads();
  for (int off = 128; off > 0; off >>= 1) {
    if (t < off) sm[t] += sm[t + off];
    __syncthreads();
  }
  if (t == 0) csum[b] = sm[0];
}

__global__ __launch_bounds__(64) void k_scan2(int* __restrict__ csum, int nch) {
  int lane = threadIdx.x & 63;
  if (nch <= 64) {
    int orig = (lane < nch) ? csum[lane] : 0;
    int v = orig;
    for (int off = 1; off < 64; off <<= 1) {
      int y = __shfl_up(v, off);
      if (lane >= off) v += y;
    }
    if (lane < nch) csum[lane] = v - orig;
  } else if (lane == 0) {
    int run = 0;
    for (int i = 0; i < nch; ++i) { int v = csum[i]; csum[i] = run; run += v; }
  }
}

__global__ __launch_bounds__(256) void k_scan3(const int* __restrict__ cnt,
                                               const int* __restrict__ csum,
                                               int* __restrict__ rowptr,
                                               int n, int E) {
  __shared__ int sm[256];
  int b = blockIdx.x, t = threadIdx.x;
  int base = b * 1024;
  int v[4], loc = 0;
#pragma unroll
  for (int k = 0; k < 4; ++k) {
    int idx = base + t * 4 + k;
    v[k] = (idx < n) ? cnt[idx] : 0;
    loc += v[k];
  }
  sm[t] = loc;
  __syncthreads();
  for (int off = 1; off < 256; off <<= 1) {
    int y = (t >= off) ? sm[t - off] : 0;
    __syncthreads();
    sm[t] += y;
    __syncthreads();
  }
  int run = csum[b] + sm[t] - loc;
#pragma unroll
  for (int k = 0; k < 4; ++k) {
    int idx = base + t * 4 + k;
    if (idx < n) { rowptr[idx] = run; run += v[k]; }
  }
  if (b == 0 && t == 0) rowptr[n] = E;
}

// bCursor[b] = rowptr[b * BK_NODES]
__global__ __launch_bounds__(256) void k_binit(const int* __restrict__ rowptr,
                                               int* __restrict__ bCursor, int nb) {
  int b = blockIdx.x * 256 + threadIdx.x;
  if (b < nb) bCursor[b] = rowptr[b << BK_SHIFT];
}

// Phase A: bucket edges by dst>>7 into bucket-contiguous runs of packed
// (dstoff<<16 | src). Writes are block-local contiguous runs -> coalesced.
__global__ __launch_bounds__(256) void k_bucketA(const int* __restrict__ src,
                                                 const int* __restrict__ dst,
                                                 int* __restrict__ bCursor,
                                                 int* __restrict__ packed,
                                                 int E, int nb) {
  __shared__ int hist[NBMAX];
  __shared__ int base[NBMAX];
  int t = threadIdx.x;
  int e0 = blockIdx.x * TILE_A;

  for (int b = t; b < nb; b += 256) hist[b] = 0;
  __syncthreads();

  for (int i = t; i < TILE_A; i += 256) {
    int e = e0 + i;
    if (e < E) atomicAdd(&hist[dst[e] >> BK_SHIFT], 1);
  }
  __syncthreads();

  for (int b = t; b < nb; b += 256) {
    int h = hist[b];
    if (h) base[b] = atomicAdd(&bCursor[b], h);
  }
  __syncthreads();

  for (int i = t; i < TILE_A; i += 256) {
    int e = e0 + i;
    if (e < E) {
      int d = dst[e];
      int bkt = d >> BK_SHIFT;
      int pos = atomicAdd(&base[bkt], 1);
      packed[pos] = (src[e] & 0xFFFF) | ((d & (BK_NODES - 1)) << 16);
    }
  }
}

// Phase B: per bucket, sort packed edges into exact CSR order via LDS
// histogram + scan + in-LDS scatter; stream out coalesced.
__global__ __launch_bounds__(256) void k_bucketB(const int* __restrict__ packed,
                                                 const int* __restrict__ rowptr,
                                                 int* __restrict__ srcSorted,
                                                 int n) {
  __shared__ int hist[BK_NODES];
  __shared__ int buf[BUFCAP];
  int t = threadIdx.x;
  int bkt = blockIdx.x;
  int n0 = bkt << BK_SHIFT;
  int n1 = n0 + BK_NODES; if (n1 > n) n1 = n;
  int beg = rowptr[n0], end = rowptr[n1];
  int cnt = end - beg;

  if (t < BK_NODES) hist[t] = 0;
  __syncthreads();

  for (int i = t; i < cnt; i += 256)
    atomicAdd(&hist[packed[beg + i] >> 16], 1);
  __syncthreads();

  if (t == 0) {            // exclusive scan of 128 counters (cheap)
    int run = 0;
#pragma unroll
    for (int j = 0; j < BK_NODES; ++j) { int v = hist[j]; hist[j] = run; run += v; }
  }
  __syncthreads();

  if (cnt <= BUFCAP) {
    for (int i = t; i < cnt; i += 256) {
      int p = packed[beg + i];
      int pos = atomicAdd(&hist[p >> 16], 1);
      buf[pos] = p & 0xFFFF;
    }
    __syncthreads();
    for (int i = t; i < cnt; i += 256) srcSorted[beg + i] = buf[i];
  } else {                 // never expected; correctness fallback
    for (int i = t; i < cnt; i += 256) {
      int p = packed[beg + i];
      int pos = atomicAdd(&hist[p >> 16], 1);
      srcSorted[beg + pos] = p & 0xFFFF;
    }
  }
}

// ---------------- aggregation (CSR, wave per node) ----------------

__global__ __launch_bounds__(256) void k_aggcsr(const float* __restrict__ X,
                                                const int* __restrict__ srcSorted,
                                                const int* __restrict__ rowptr,
                                                const float* __restrict__ dinv,
                                                float* __restrict__ out, int n) {
  int wave = (blockIdx.x * 256 + threadIdx.x) >> 6;
  int lane = threadIdx.x & 63;
  if (wave >= n) return;
  int beg = rowptr[wave], end = rowptr[wave + 1];
  float ax = 0.f, ay = 0.f;
  int j = beg;
  for (; j + 3 < end; j += 4) {
    int s0 = srcSorted[j], s1 = srcSorted[j + 1];
    int s2 = srcSorted[j + 2], s3 = srcSorted[j + 3];
    float w0 = dinv[s0], w1 = dinv[s1], w2 = dinv[s2], w3 = dinv[s3];
    float2 v0 = ((const float2*)(X + (size_t)s0 * D))[lane];
    float2 v1 = ((const float2*)(X + (size_t)s1 * D))[lane];
    float2 v2 = ((const float2*)(X + (size_t)s2 * D))[lane];
    float2 v3 = ((const float2*)(X + (size_t)s3 * D))[lane];
    ax += v0.x * w0 + v1.x * w1 + v2.x * w2 + v3.x * w3;
    ay += v0.y * w0 + v1.y * w1 + v2.y * w2 + v3.y * w3;
  }
  for (; j < end; ++j) {
    int s = srcSorted[j];
    float w = dinv[s];
    float2 v = ((const float2*)(X + (size_t)s * D))[lane];
    ax += v.x * w;
    ay += v.y * w;
  }
  float dn = dinv[wave];
  float2 sv = ((const float2*)(X + (size_t)wave * D))[lane];
  float2 o;
  o.x = ax * dn + sv.x * dn * dn;
  o.y = ay * dn + sv.y * dn * dn;
  ((float2*)(out + (size_t)wave * D))[lane] = o;
}

// ---------------- atomic fallback helpers ----------------

__global__ __launch_bounds__(256) void k_deg_f(const int* __restrict__ dst,
                                               float* __restrict__ deg, int E) {
  int i = blockIdx.x * 256 + threadIdx.x;
  if (i < E) atomicAdd(&deg[dst[i]], 1.0f);
}

__global__ __launch_bounds__(256) void k_dinv_f(float* __restrict__ deg, int n) {
  int i = blockIdx.x * 256 + threadIdx.x;
  if (i < n) deg[i] = rsqrtf(deg[i] + 1.0f);
}

__global__ __launch_bounds__(256) void k_selfmul(const float* __restrict__ X,
                                                 const float* __restrict__ dinv,
                                                 float* __restrict__ out, int n) {
  int i = blockIdx.x * 256 + threadIdx.x;
  if (i >= n * 32) return;
  int r = i >> 5, c4 = (i & 31) << 2;
  float di = dinv[r];
  float s = di * di;
  float4 h = *(const float4*)(X + (size_t)r * D + c4);
  h.x *= s; h.y *= s; h.z *= s; h.w *= s;
  *(float4*)(out + (size_t)r * D + c4) = h;
}

__global__ __launch_bounds__(256) void k_aggatomic(const float* __restrict__ X,
                                                   const int* __restrict__ src,
                                                   const int* __restrict__ dst,
                                                   const float* __restrict__ dinv,
                                                   float* __restrict__ out, int E) {
  int gid = blockIdx.x * 256 + threadIdx.x;
  int wave = gid >> 6;
  int lane = threadIdx.x & 63;
  int nw = (gridDim.x * 256) >> 6;
  for (int e = wave; e < E; e += nw) {
    int s = src[e], d = dst[e];
    float nrm = dinv[s] * dinv[d];
    float2 v = ((const float2*)(X + (size_t)s * D))[lane];
    float* op = out + (size_t)d * D + lane * 2;
    atomicAdd(op, v.x * nrm);
    atomicAdd(op + 1, v.y * nrm);
  }
}

// ---------------- GEMM: C = X @ W^T + b, optional relu(C*mask) ----------------

__global__ __launch_bounds__(256) void k_gemm128(const float* __restrict__ X,
                                                 const float* __restrict__ W,
                                                 const float* __restrict__ bias,
                                                 const float* __restrict__ mask,
                                                 float* __restrict__ C, int nrows) {
  __shared__ float Xs[64][132];
  __shared__ float Ws[32][128];

  int tid = threadIdx.x;
  int row0 = blockIdx.x * 64;

  for (int t = tid; t < 2048; t += 256) {
    int r = t >> 5;
    int c4 = (t & 31) << 2;
    int gr = row0 + r;
    float4 v = make_float4(0.f, 0.f, 0.f, 0.f);
    if (gr < nrows) v = *(const float4*)(X + (size_t)gr * D + c4);
    Xs[r][c4 + 0] = v.x; Xs[r][c4 + 1] = v.y;
    Xs[r][c4 + 2] = v.z; Xs[r][c4 + 3] = v.w;
  }

  float acc[4][8];
#pragma unroll
  for (int i = 0; i < 4; ++i)
#pragma unroll
    for (int j = 0; j < 8; ++j) acc[i][j] = 0.f;

  int ty = tid >> 4, tx = tid & 15;
  int r0 = ty << 2, c0 = tx << 3;

  for (int k0 = 0; k0 < 128; k0 += 32) {
    int j = tid >> 1;
    int kkb = (tid & 1) << 4;
    const float4* wp = (const float4*)(W + j * D + k0 + kkb);
    float4 wa = wp[0], wb = wp[1], wc = wp[2], wd = wp[3];

    __syncthreads();
    Ws[kkb +  0][j] = wa.x; Ws[kkb +  1][j] = wa.y; Ws[kkb +  2][j] = wa.z; Ws[kkb +  3][j] = wa.w;
    Ws[kkb +  4][j] = wb.x; Ws[kkb +  5][j] = wb.y; Ws[kkb +  6][j] = wb.z; Ws[kkb +  7][j] = wb.w;
    Ws[kkb +  8][j] = wc.x; Ws[kkb +  9][j] = wc.y; Ws[kkb + 10][j] = wc.z; Ws[kkb + 11][j] = wc.w;
    Ws[kkb + 12][j] = wd.x; Ws[kkb + 13][j] = wd.y; Ws[kkb + 14][j] = wd.z; Ws[kkb + 15][j] = wd.w;
    __syncthreads();

#pragma unroll
    for (int kk = 0; kk < 32; ++kk) {
      float xi[4];
      xi[0] = Xs[r0 + 0][k0 + kk];
      xi[1] = Xs[r0 + 1][k0 + kk];
      xi[2] = Xs[r0 + 2][k0 + kk];
      xi[3] = Xs[r0 + 3][k0 + kk];
      float4 wv0 = *(const float4*)(&Ws[kk][c0]);
      float4 wv1 = *(const float4*)(&Ws[kk][c0 + 4]);
      float wf[8] = {wv0.x, wv0.y, wv0.z, wv0.w, wv1.x, wv1.y, wv1.z, wv1.w};
#pragma unroll
      for (int i = 0; i < 4; ++i)
#pragma unroll
        for (int jj = 0; jj < 8; ++jj) acc[i][jj] += xi[i] * wf[jj];
    }
  }

  float4 bv0 = *(const float4*)(bias + c0);
  float4 bv1 = *(const float4*)(bias + c0 + 4);

#pragma unroll
  for (int i = 0; i < 4; ++i) {
    int gr = row0 + r0 + i;
    if (gr < nrows) {
      float4 v0 = make_float4(acc[i][0] + bv0.x, acc[i][1] + bv0.y,
                              acc[i][2] + bv0.z, acc[i][3] + bv0.w);
      float4 v1 = make_float4(acc[i][4] + bv1.x, acc[i][5] + bv1.y,
                              acc[i][6] + bv1.z, acc[i][7] + bv1.w);
      if (mask) {
        float4 m0 = *(const float4*)(mask + (size_t)gr * D + c0);
        float4 m1 = *(const float4*)(mask + (size_t)gr * D + c0 + 4);
        v0.x = fmaxf(v0.x * m0.x, 0.f); v0.y = fmaxf(v0.y * m0.y, 0.f);
        v0.z = fmaxf(v0.z * m0.z, 0.f); v0.w = fmaxf(v0.w * m0.w, 0.f);
        v1.x = fmaxf(v1.x * m1.x, 0.f); v1.y = fmaxf(v1.y * m1.y, 0.f);
        v1.w = fmaxf(v1.w * m1.w, 0.f); v1.z = fmaxf(v1.z * m1.z, 0.f);
      }
      *(float4*)(C + (size_t)gr * D + c0)     = v0;
      *(float4*)(C + (size_t)gr * D + c0 + 4) = v1;
    }
  }
}

// ---------------- launch ----------------

extern "C" void kernel_launch(void* const* d_in, const int* in_sizes, int n_in,
                              void* d_out, int out_size, void* d_ws, size_t ws_size,
                              hipStream_t stream) {
  const float* x    = (const float*)d_in[0];
  const int*   ei   = (const int*)d_in[1];
  const float* mask = (const float*)d_in[2];
  const float* W0   = (const float*)d_in[3];
  const float* b0   = (const float*)d_in[4];
  const float* W1   = (const float*)d_in[5];
  const float* b1   = (const float*)d_in[6];
  const float* W2   = (const float*)d_in[7];
  const float* b2   = (const float*)d_in[8];

  const int N = in_sizes[0] / D;
  const int E = in_sizes[1] / 2;
  const int* srcv = ei;
  const int* dstv = ei + E;

  float* out  = (float*)d_out;
  float* outA = out;                    // x_
  float* outB = out + (size_t)N * D;    // x2

  const size_t featBytes = (size_t)N * D * sizeof(float);
  const int gElem  = (N * 32 + 255) / 256;
  const int gGemm  = (N + 63) / 64;
  const int gEdge  = (E + 255) / 256;
  const int gNode  = (N + 255) / 256;
  const int gWaveN = (N + 3) / 4;
  const int nch    = (N + 1023) / 1024;
  const int nb     = (N + BK_NODES - 1) >> BK_SHIFT;
  const int gBA    = (E + TILE_A - 1) / TILE_A;

  char* w = (char*)d_ws;
  int*   cnt       = (int*)(w);                         // N ints
  float* dinv      = (float*)(w + 0x40000);             // N f32
  int*   rowptr    = (int*)(w + 0x80000);               // N+1 ints
  int*   csum      = (int*)(w + 0xC0000);               // <=64 ints
  int*   bCursor   = (int*)(w + 0xC1000);               // <=512 ints
  float* bufA      = (float*)(w + 0x100000);            // N*D f32 (first E ints alias packed)
  int*   packed    = (int*)bufA;                        // E ints (consumed before bufA written)
  int*   srcSorted = (int*)(w + 0x100000 + featBytes);  // E ints
  float* bufB      = (float*)(w + 0x100000 + featBytes + (size_t)E * sizeof(int));
  size_t need = 0x100000 + featBytes * 2 + (size_t)E * sizeof(int);

  if (ws_size >= need && N <= 65536 && nb <= NBMAX &&
      (size_t)E * sizeof(int) <= featBytes) {
    // ---- CSR path with bucketed sort ----
    hipMemsetAsync(cnt, 0, (size_t)N * sizeof(int), stream);
    k_hist<<<gEdge, 256, 0, stream>>>(dstv, cnt, E);
    k_dinv<<<gNode, 256, 0, stream>>>(cnt, dinv, N);
    k_scan1<<<nch, 256, 0, stream>>>(cnt, csum, N);
    k_scan2<<<1, 64, 0, stream>>>(csum, nch);
    k_scan3<<<nch, 256, 0, stream>>>(cnt, csum, rowptr, N, E);
    k_binit<<<(nb + 255) / 256, 256, 0, stream>>>(rowptr, bCursor, nb);
    k_bucketA<<<gBA, 256, 0, stream>>>(srcv, dstv, bCursor, packed, E, nb);
    k_bucketB<<<nb, 256, 0, stream>>>(packed, rowptr, srcSorted, N);

    // layer 0: h = relu((agg(x) @ W0^T + b0) * mask)
    k_aggcsr<<<gWaveN, 256, 0, stream>>>(x, srcSorted, rowptr, dinv, bufA, N);
    k_gemm128<<<gGemm, 256, 0, stream>>>(bufA, W0, b0, mask, bufB, N);
    // layers 1+2 share g = agg(h)
    k_aggcsr<<<gWaveN, 256, 0, stream>>>(bufB, srcSorted, rowptr, dinv, bufA, N);
    k_gemm128<<<gGemm, 256, 0, stream>>>(bufA, W1, b1, nullptr, outA, N);
    k_gemm128<<<gGemm, 256, 0, stream>>>(bufA, W2, b2, nullptr, outB, N);
  } else {
    // ---- atomic fallback (commuted, 2 aggs) ----
    float* fdinv = (float*)(w);
    float* fA    = (float*)(w + 0x40000);
    float* fB    = (float*)((char*)fA + featBytes);
    hipMemsetAsync(fdinv, 0, (size_t)N * sizeof(float), stream);
    k_deg_f<<<gEdge, 256, 0, stream>>>(dstv, fdinv, E);
    k_dinv_f<<<gNode, 256, 0, stream>>>(fdinv, N);
    k_selfmul<<<gElem, 256, 0, stream>>>(x, fdinv, fA, N);
    k_aggatomic<<<4096, 256, 0, stream>>>(x, srcv, dstv, fdinv, fA, E);
    k_gemm128<<<gGemm, 256, 0, stream>>>(fA, W0, b0, mask, fB, N);
    k_selfmul<<<gElem, 256, 0, stream>>>(fB, fdinv, fA, N);
    k_aggatomic<<<4096, 256, 0, stream>>>(fB, srcv, dstv, fdinv, fA, E);
    k_gemm128<<<gGemm, 256, 0, stream>>>(fA, W1, b1, nullptr, outA, N);
    k_gemm128<<<gGemm, 256, 0, stream>>>(fA, W2, b2, nullptr, outB, N);
  }
}

// Round 6
// 397.551 us; speedup vs baseline: 10.4222x; 1.2171x over previous
//
#include <hip/hip_runtime.h>

// ---------------------------------------------------------------------------
// GCN encoder, N=50000, E=1.6M, D=128.
// Round 6: bf16 gather tables (halves agg fetch traffic). Layer 0 reordered
// GEMM-first so both aggregations gather bf16; bias+dropout+relu fused into
// agg#1 epilogue. CSR build unchanged from round 5.
// ---------------------------------------------------------------------------

#define D 128
#define BK_SHIFT 7            // 128 nodes per bucket
#define BK_NODES 128
#define NBMAX 512             // max buckets (N <= 65536)
#define BUFCAP 6144           // LDS staging capacity (edges) in k_bucketB
#define TILE_A 16384          // edges per block in k_bucketA

static __device__ __forceinline__ unsigned f2bf(float f) {
  union { float f; unsigned u; } v; v.f = f;
  unsigned r = v.u + 0x7FFF + ((v.u >> 16) & 1);   // round to nearest even
  return r >> 16;
}
static __device__ __forceinline__ float bflo(unsigned u) {  // low bf16 of pair
  return __uint_as_float(u << 16);
}
static __device__ __forceinline__ float bfhi(unsigned u) {  // high bf16 of pair
  return __uint_as_float(u & 0xFFFF0000u);
}

// ---------------- CSR build ----------------

__global__ __launch_bounds__(256) void k_hist(const int* __restrict__ dst,
                                              int* __restrict__ cnt, int E) {
  int i = blockIdx.x * 256 + threadIdx.x;
  if (i < E) atomicAdd(&cnt[dst[i]], 1);
}

__global__ __launch_bounds__(256) void k_dinv(const int* __restrict__ cnt,
                                              float* __restrict__ dinv, int n) {
  int i = blockIdx.x * 256 + threadIdx.x;
  if (i < n) dinv[i] = rsqrtf((float)cnt[i] + 1.0f);
}

__global__ __launch_bounds__(256) void k_scan1(const int* __restrict__ cnt,
                                               int* __restrict__ csum, int n) {
  __shared__ int sm[256];
  int b = blockIdx.x, t = threadIdx.x;
  int base = b * 1024, s = 0;
  for (int i = t; i < 1024; i += 256) {
    int idx = base + i;
    s += (idx < n) ? cnt[idx] : 0;
  }
  sm[t] = s;
  __syncthreads();
  for (int off = 128; off > 0; off >>= 1) {
    if (t < off) sm[t] += sm[t + off];
    __syncthreads();
  }
  if (t == 0) csum[b] = sm[0];
}

__global__ __launch_bounds__(64) void k_scan2(int* __restrict__ csum, int nch) {
  int lane = threadIdx.x & 63;
  if (nch <= 64) {
    int orig = (lane < nch) ? csum[lane] : 0;
    int v = orig;
    for (int off = 1; off < 64; off <<= 1) {
      int y = __shfl_up(v, off);
      if (lane >= off) v += y;
    }
    if (lane < nch) csum[lane] = v - orig;
  } else if (lane == 0) {
    int run = 0;
    for (int i = 0; i < nch; ++i) { int v = csum[i]; csum[i] = run; run += v; }
  }
}

__global__ __launch_bounds__(256) void k_scan3(const int* __restrict__ cnt,
                                               const int* __restrict__ csum,
                                               int* __restrict__ rowptr,
                                               int n, int E) {
  __shared__ int sm[256];
  int b = blockIdx.x, t = threadIdx.x;
  int base = b * 1024;
  int v[4], loc = 0;
#pragma unroll
  for (int k = 0; k < 4; ++k) {
    int idx = base + t * 4 + k;
    v[k] = (idx < n) ? cnt[idx] : 0;
    loc += v[k];
  }
  sm[t] = loc;
  __syncthreads();
  for (int off = 1; off < 256; off <<= 1) {
    int y = (t >= off) ? sm[t - off] : 0;
    __syncthreads();
    sm[t] += y;
    __syncthreads();
  }
  int run = csum[b] + sm[t] - loc;
#pragma unroll
  for (int k = 0; k < 4; ++k) {
    int idx = base + t * 4 + k;
    if (idx < n) { rowptr[idx] = run; run += v[k]; }
  }
  if (b == 0 && t == 0) rowptr[n] = E;
}

__global__ __launch_bounds__(256) void k_binit(const int* __restrict__ rowptr,
                                               int* __restrict__ bCursor, int nb) {
  int b = blockIdx.x * 256 + threadIdx.x;
  if (b < nb) bCursor[b] = rowptr[b << BK_SHIFT];
}

__global__ __launch_bounds__(256) void k_bucketA(const int* __restrict__ src,
                                                 const int* __restrict__ dst,
                                                 int* __restrict__ bCursor,
                                                 int* __restrict__ packed,
                                                 int E, int nb) {
  __shared__ int hist[NBMAX];
  __shared__ int base[NBMAX];
  int t = threadIdx.x;
  int e0 = blockIdx.x * TILE_A;

  for (int b = t; b < nb; b += 256) hist[b] = 0;
  __syncthreads();

  for (int i = t; i < TILE_A; i += 256) {
    int e = e0 + i;
    if (e < E) atomicAdd(&hist[dst[e] >> BK_SHIFT], 1);
  }
  __syncthreads();

  for (int b = t; b < nb; b += 256) {
    int h = hist[b];
    if (h) base[b] = atomicAdd(&bCursor[b], h);
  }
  __syncthreads();

  for (int i = t; i < TILE_A; i += 256) {
    int e = e0 + i;
    if (e < E) {
      int d = dst[e];
      int bkt = d >> BK_SHIFT;
      int pos = atomicAdd(&base[bkt], 1);
      packed[pos] = (src[e] & 0xFFFF) | ((d & (BK_NODES - 1)) << 16);
    }
  }
}

__global__ __launch_bounds__(256) void k_bucketB(const int* __restrict__ packed,
                                                 const int* __restrict__ rowptr,
                                                 int* __restrict__ srcSorted,
                                                 int n) {
  __shared__ int hist[BK_NODES];
  __shared__ int buf[BUFCAP];
  int t = threadIdx.x;
  int bkt = blockIdx.x;
  int n0 = bkt << BK_SHIFT;
  int n1 = n0 + BK_NODES; if (n1 > n) n1 = n;
  int beg = rowptr[n0], end = rowptr[n1];
  int cnt = end - beg;

  if (t < BK_NODES) hist[t] = 0;
  __syncthreads();

  for (int i = t; i < cnt; i += 256)
    atomicAdd(&hist[packed[beg + i] >> 16], 1);
  __syncthreads();

  if (t == 0) {
    int run = 0;
#pragma unroll
    for (int j = 0; j < BK_NODES; ++j) { int v = hist[j]; hist[j] = run; run += v; }
  }
  __syncthreads();

  if (cnt <= BUFCAP) {
    for (int i = t; i < cnt; i += 256) {
      int p = packed[beg + i];
      int pos = atomicAdd(&hist[p >> 16], 1);
      buf[pos] = p & 0xFFFF;
    }
    __syncthreads();
    for (int i = t; i < cnt; i += 256) srcSorted[beg + i] = buf[i];
  } else {
    for (int i = t; i < cnt; i += 256) {
      int p = packed[beg + i];
      int pos = atomicAdd(&hist[p >> 16], 1);
      srcSorted[beg + pos] = p & 0xFFFF;
    }
  }
}

// ---------------- aggregation (CSR, wave per node, bf16 gather) -------------
// EPI=0: out = agg (f32).  EPI=1: out = bf16( relu((agg + bias) * mask) ).

template <int EPI>
__global__ __launch_bounds__(256) void k_aggb(const unsigned* __restrict__ Hb,
                                              const int* __restrict__ srcSorted,
                                              const int* __restrict__ rowptr,
                                              const float* __restrict__ dinv,
                                              const float* __restrict__ bias,
                                              const float* __restrict__ mask,
                                              float* __restrict__ outF,
                                              unsigned* __restrict__ outB,
                                              int n) {
  int wave = (blockIdx.x * 256 + threadIdx.x) >> 6;
  int lane = threadIdx.x & 63;
  if (wave >= n) return;
  int beg = rowptr[wave], end = rowptr[wave + 1];
  float ax = 0.f, ay = 0.f;
  int j = beg;
  for (; j + 3 < end; j += 4) {
    int s0 = srcSorted[j], s1 = srcSorted[j + 1];
    int s2 = srcSorted[j + 2], s3 = srcSorted[j + 3];
    float w0 = dinv[s0], w1 = dinv[s1], w2 = dinv[s2], w3 = dinv[s3];
    unsigned u0 = Hb[(size_t)s0 * 64 + lane];
    unsigned u1 = Hb[(size_t)s1 * 64 + lane];
    unsigned u2 = Hb[(size_t)s2 * 64 + lane];
    unsigned u3 = Hb[(size_t)s3 * 64 + lane];
    ax += bflo(u0) * w0 + bflo(u1) * w1 + bflo(u2) * w2 + bflo(u3) * w3;
    ay += bfhi(u0) * w0 + bfhi(u1) * w1 + bfhi(u2) * w2 + bfhi(u3) * w3;
  }
  for (; j < end; ++j) {
    int s = srcSorted[j];
    float w = dinv[s];
    unsigned u = Hb[(size_t)s * 64 + lane];
    ax += bflo(u) * w;
    ay += bfhi(u) * w;
  }
  float dn = dinv[wave];
  unsigned us = Hb[(size_t)wave * 64 + lane];
  float ox = ax * dn + bflo(us) * dn * dn;
  float oy = ay * dn + bfhi(us) * dn * dn;
  if (EPI == 1) {
    float2 bv = ((const float2*)bias)[lane];
    float2 mv = ((const float2*)mask)[(size_t)wave * 64 + lane];
    float hx = fmaxf((ox + bv.x) * mv.x, 0.f);
    float hy = fmaxf((oy + bv.y) * mv.y, 0.f);
    outB[(size_t)wave * 64 + lane] = f2bf(hx) | (f2bf(hy) << 16);
  } else {
    ((float2*)outF)[(size_t)wave * 64 + lane] = make_float2(ox, oy);
  }
}

// ---------------- GEMM: C = X @ W^T (+ b), f32 or bf16 out ------------------

template <bool BF16OUT>
__global__ __launch_bounds__(256) void k_gemm128(const float* __restrict__ X,
                                                 const float* __restrict__ W,
                                                 const float* __restrict__ bias,
                                                 float* __restrict__ Cf,
                                                 unsigned short* __restrict__ Cb,
                                                 int nrows) {
  __shared__ float Xs[64][132];
  __shared__ float Ws[32][128];

  int tid = threadIdx.x;
  int row0 = blockIdx.x * 64;

  for (int t = tid; t < 2048; t += 256) {
    int r = t >> 5;
    int c4 = (t & 31) << 2;
    int gr = row0 + r;
    float4 v = make_float4(0.f, 0.f, 0.f, 0.f);
    if (gr < nrows) v = *(const float4*)(X + (size_t)gr * D + c4);
    Xs[r][c4 + 0] = v.x; Xs[r][c4 + 1] = v.y;
    Xs[r][c4 + 2] = v.z; Xs[r][c4 + 3] = v.w;
  }

  float acc[4][8];
#pragma unroll
  for (int i = 0; i < 4; ++i)
#pragma unroll
    for (int j = 0; j < 8; ++j) acc[i][j] = 0.f;

  int ty = tid >> 4, tx = tid & 15;
  int r0 = ty << 2, c0 = tx << 3;

  for (int k0 = 0; k0 < 128; k0 += 32) {
    int j = tid >> 1;
    int kkb = (tid & 1) << 4;
    const float4* wp = (const float4*)(W + j * D + k0 + kkb);
    float4 wa = wp[0], wb = wp[1], wc = wp[2], wd = wp[3];

    __syncthreads();
    Ws[kkb +  0][j] = wa.x; Ws[kkb +  1][j] = wa.y; Ws[kkb +  2][j] = wa.z; Ws[kkb +  3][j] = wa.w;
    Ws[kkb +  4][j] = wb.x; Ws[kkb +  5][j] = wb.y; Ws[kkb +  6][j] = wb.z; Ws[kkb +  7][j] = wb.w;
    Ws[kkb +  8][j] = wc.x; Ws[kkb +  9][j] = wc.y; Ws[kkb + 10][j] = wc.z; Ws[kkb + 11][j] = wc.w;
    Ws[kkb + 12][j] = wd.x; Ws[kkb + 13][j] = wd.y; Ws[kkb + 14][j] = wd.z; Ws[kkb + 15][j] = wd.w;
    __syncthreads();

#pragma unroll
    for (int kk = 0; kk < 32; ++kk) {
      float xi[4];
      xi[0] = Xs[r0 + 0][k0 + kk];
      xi[1] = Xs[r0 + 1][k0 + kk];
      xi[2] = Xs[r0 + 2][k0 + kk];
      xi[3] = Xs[r0 + 3][k0 + kk];
      float4 wv0 = *(const float4*)(&Ws[kk][c0]);
      float4 wv1 = *(const float4*)(&Ws[kk][c0 + 4]);
      float wf[8] = {wv0.x, wv0.y, wv0.z, wv0.w, wv1.x, wv1.y, wv1.z, wv1.w};
#pragma unroll
      for (int i = 0; i < 4; ++i)
#pragma unroll
        for (int jj = 0; jj < 8; ++jj) acc[i][jj] += xi[i] * wf[jj];
    }
  }

  float4 bv0 = make_float4(0.f, 0.f, 0.f, 0.f);
  float4 bv1 = make_float4(0.f, 0.f, 0.f, 0.f);
  if (bias) {
    bv0 = *(const float4*)(bias + c0);
    bv1 = *(const float4*)(bias + c0 + 4);
  }

#pragma unroll
  for (int i = 0; i < 4; ++i) {
    int gr = row0 + r0 + i;
    if (gr < nrows) {
      float o[8];
      o[0] = acc[i][0] + bv0.x; o[1] = acc[i][1] + bv0.y;
      o[2] = acc[i][2] + bv0.z; o[3] = acc[i][3] + bv0.w;
      o[4] = acc[i][4] + bv1.x; o[5] = acc[i][5] + bv1.y;
      o[6] = acc[i][6] + bv1.z; o[7] = acc[i][7] + bv1.w;
      if (BF16OUT) {
        uint4 pk;
        pk.x = f2bf(o[0]) | (f2bf(o[1]) << 16);
        pk.y = f2bf(o[2]) | (f2bf(o[3]) << 16);
        pk.z = f2bf(o[4]) | (f2bf(o[5]) << 16);
        pk.w = f2bf(o[6]) | (f2bf(o[7]) << 16);
        *(uint4*)(Cb + (size_t)gr * D + c0) = pk;
      } else {
        *(float4*)(Cf + (size_t)gr * D + c0)     = make_float4(o[0], o[1], o[2], o[3]);
        *(float4*)(Cf + (size_t)gr * D + c0 + 4) = make_float4(o[4], o[5], o[6], o[7]);
      }
    }
  }
}

// ---------------- atomic fallback helpers (round-2 path) --------------------

__global__ __launch_bounds__(256) void k_deg_f(const int* __restrict__ dst,
                                               float* __restrict__ deg, int E) {
  int i = blockIdx.x * 256 + threadIdx.x;
  if (i < E) atomicAdd(&deg[dst[i]], 1.0f);
}

__global__ __launch_bounds__(256) void k_dinv_f(float* __restrict__ deg, int n) {
  int i = blockIdx.x * 256 + threadIdx.x;
  if (i < n) deg[i] = rsqrtf(deg[i] + 1.0f);
}

__global__ __launch_bounds__(256) void k_selfmul(const float* __restrict__ X,
                                                 const float* __restrict__ dinv,
                                                 float* __restrict__ out, int n) {
  int i = blockIdx.x * 256 + threadIdx.x;
  if (i >= n * 32) return;
  int r = i >> 5, c4 = (i & 31) << 2;
  float di = dinv[r];
  float s = di * di;
  float4 h = *(const float4*)(X + (size_t)r * D + c4);
  h.x *= s; h.y *= s; h.z *= s; h.w *= s;
  *(float4*)(out + (size_t)r * D + c4) = h;
}

__global__ __launch_bounds__(256) void k_relumask(float* __restrict__ h,
                                                  const float* __restrict__ mask, int n) {
  int i = blockIdx.x * 256 + threadIdx.x;
  if (i >= n * 32) return;
  float4 v = *(const float4*)(h + (size_t)i * 4);
  float4 m = *(const float4*)(mask + (size_t)i * 4);
  v.x = fmaxf(v.x * m.x, 0.f);
  v.y = fmaxf(v.y * m.y, 0.f);
  v.z = fmaxf(v.z * m.z, 0.f);
  v.w = fmaxf(v.w * m.w, 0.f);
  *(float4*)(h + (size_t)i * 4) = v;
}

__global__ __launch_bounds__(256) void k_aggatomic(const float* __restrict__ X,
                                                   const int* __restrict__ src,
                                                   const int* __restrict__ dst,
                                                   const float* __restrict__ dinv,
                                                   float* __restrict__ out, int E) {
  int gid = blockIdx.x * 256 + threadIdx.x;
  int wave = gid >> 6;
  int lane = threadIdx.x & 63;
  int nw = (gridDim.x * 256) >> 6;
  for (int e = wave; e < E; e += nw) {
    int s = src[e], d = dst[e];
    float nrm = dinv[s] * dinv[d];
    float2 v = ((const float2*)(X + (size_t)s * D))[lane];
    float* op = out + (size_t)d * D + lane * 2;
    atomicAdd(op, v.x * nrm);
    atomicAdd(op + 1, v.y * nrm);
  }
}

__global__ __launch_bounds__(256) void k_addbias(float* __restrict__ C,
                                                 const float* __restrict__ bias, int n) {
  int i = blockIdx.x * 256 + threadIdx.x;
  if (i >= n * 32) return;
  int c4 = (i & 31) << 2;
  float4 v = *(const float4*)(C + (size_t)i * 4);
  float4 b = *(const float4*)(bias + c4);
  v.x += b.x; v.y += b.y; v.z += b.z; v.w += b.w;
  *(float4*)(C + (size_t)i * 4) = v;
}

// ---------------- launch ----------------

extern "C" void kernel_launch(void* const* d_in, const int* in_sizes, int n_in,
                              void* d_out, int out_size, void* d_ws, size_t ws_size,
                              hipStream_t stream) {
  const float* x    = (const float*)d_in[0];
  const int*   ei   = (const int*)d_in[1];
  const float* mask = (const float*)d_in[2];
  const float* W0   = (const float*)d_in[3];
  const float* b0   = (const float*)d_in[4];
  const float* W1   = (const float*)d_in[5];
  const float* b1   = (const float*)d_in[6];
  const float* W2   = (const float*)d_in[7];
  const float* b2   = (const float*)d_in[8];

  const int N = in_sizes[0] / D;
  const int E = in_sizes[1] / 2;
  const int* srcv = ei;
  const int* dstv = ei + E;

  float* out  = (float*)d_out;
  float* outA = out;                    // x_
  float* outB = out + (size_t)N * D;    // x2

  const size_t featBytes  = (size_t)N * D * sizeof(float);   // 25.6 MB
  const size_t featBytesH = (size_t)N * D * sizeof(short);   // 12.8 MB
  const int gGemm  = (N + 63) / 64;
  const int gEdge  = (E + 255) / 256;
  const int gNode  = (N + 255) / 256;
  const int gWaveN = (N + 3) / 4;
  const int gElem  = (N * 32 + 255) / 256;
  const int nch    = (N + 1023) / 1024;
  const int nb     = (N + BK_NODES - 1) >> BK_SHIFT;
  const int gBA    = (E + TILE_A - 1) / TILE_A;

  // compact cumulative workspace layout (256 B aligned)
  auto align256 = [](size_t v) { return (v + 255) & ~(size_t)255; };
  char* w = (char*)d_ws;
  size_t off = 0;
  int*   cnt       = (int*)(w + off);  off = align256(off + (size_t)N * 4);
  float* dinv      = (float*)(w + off); off = align256(off + (size_t)N * 4);
  int*   rowptr    = (int*)(w + off);  off = align256(off + ((size_t)N + 1) * 4);
  int*   csum      = (int*)(w + off);  off = align256(off + 64 * 4);
  int*   bCursor   = (int*)(w + off);  off = align256(off + NBMAX * 4);
  int*   srcSorted = (int*)(w + off);  off = align256(off + (size_t)E * 4);
  float* g         = (float*)(w + off); off = align256(off + featBytes);
  int*   packed    = (int*)g;          // aliases g: consumed by bucketB before g written
  unsigned* h0bf   = (unsigned*)(w + off); off = align256(off + featBytesH);
  unsigned* hbf    = (unsigned*)(w + off); off = align256(off + featBytesH);
  size_t need = off;

  if (ws_size >= need && N <= 65536 && nb <= NBMAX &&
      (size_t)E * sizeof(int) <= featBytes) {
    // ---- CSR build ----
    hipMemsetAsync(cnt, 0, (size_t)N * sizeof(int), stream);
    k_hist<<<gEdge, 256, 0, stream>>>(dstv, cnt, E);
    k_dinv<<<gNode, 256, 0, stream>>>(cnt, dinv, N);
    k_scan1<<<nch, 256, 0, stream>>>(cnt, csum, N);
    k_scan2<<<1, 64, 0, stream>>>(csum, nch);
    k_scan3<<<nch, 256, 0, stream>>>(cnt, csum, rowptr, N, E);
    k_binit<<<(nb + 255) / 256, 256, 0, stream>>>(rowptr, bCursor, nb);
    k_bucketA<<<gBA, 256, 0, stream>>>(srcv, dstv, bCursor, packed, E, nb);
    k_bucketB<<<nb, 256, 0, stream>>>(packed, rowptr, srcSorted, N);

    // layer 0 (GEMM-first): h0 = x @ W0^T  (bf16)
    k_gemm128<true><<<gGemm, 256, 0, stream>>>(x, W0, nullptr, nullptr,
                                               (unsigned short*)h0bf, N);
    // h = bf16( relu((agg(h0) + b0) * mask) )
    k_aggb<1><<<gWaveN, 256, 0, stream>>>(h0bf, srcSorted, rowptr, dinv,
                                          b0, mask, nullptr, hbf, N);
    // g = agg(h)  (f32)
    k_aggb<0><<<gWaveN, 256, 0, stream>>>(hbf, srcSorted, rowptr, dinv,
                                          nullptr, nullptr, g, nullptr, N);
    // x_ = g @ W1^T + b1 ; x2 = g @ W2^T + b2
    k_gemm128<false><<<gGemm, 256, 0, stream>>>(g, W1, b1, outA, nullptr, N);
    k_gemm128<false><<<gGemm, 256, 0, stream>>>(g, W2, b2, outB, nullptr, N);
  } else {
    // ---- atomic fallback (commuted, 2 aggs, all f32) ----
    float* fdinv = (float*)(w);
    float* fA    = (float*)(w + 0x40000);
    float* fB    = (float*)((char*)fA + featBytes);
    hipMemsetAsync(fdinv, 0, (size_t)N * sizeof(float), stream);
    k_deg_f<<<gEdge, 256, 0, stream>>>(dstv, fdinv, E);
    k_dinv_f<<<gNode, 256, 0, stream>>>(fdinv, N);
    // h0 = x @ W0^T (f32), then out0 = agg(h0) + b0, h = relu(out0*mask)
    k_gemm128<false><<<gGemm, 256, 0, stream>>>(x, W0, nullptr, fB, nullptr, N);
    k_selfmul<<<gElem, 256, 0, stream>>>(fB, fdinv, fA, N);
    k_aggatomic<<<4096, 256, 0, stream>>>(fB, srcv, dstv, fdinv, fA, E);
    k_addbias<<<gElem, 256, 0, stream>>>(fA, b0, N);
    k_relumask<<<gElem, 256, 0, stream>>>(fA, mask, N);
    // g = agg(h)
    k_selfmul<<<gElem, 256, 0, stream>>>(fA, fdinv, fB, N);
    k_aggatomic<<<4096, 256, 0, stream>>>(fA, srcv, dstv, fdinv, fB, E);
    k_gemm128<false><<<gGemm, 256, 0, stream>>>(fB, W1, b1, outA, nullptr, N);
    k_gemm128<false><<<gGemm, 256, 0, stream>>>(fB, W2, b2, outB, nullptr, N);
  }
}

// Round 7
// 367.344 us; speedup vs baseline: 11.2792x; 1.0822x over previous
//
#include <hip/hip_runtime.h>

// ---------------------------------------------------------------------------
// GCN encoder, N=50000, E=1.6M, D=128.
// Round 7: fix k_bucketA latency-bound occupancy (TILE_A 16384->2048: 98->782
// blocks; was 3% occupancy, 80us). bucketB to 512 threads. Rest unchanged.
// ---------------------------------------------------------------------------

#define D 128
#define BK_SHIFT 7            // 128 nodes per bucket
#define BK_NODES 128
#define NBMAX 512             // max buckets (N <= 65536)
#define BUFCAP 6144           // LDS staging capacity (edges) in k_bucketB
#define TILE_A 2048           // edges per block in k_bucketA (occupancy!)

static __device__ __forceinline__ unsigned f2bf(float f) {
  union { float f; unsigned u; } v; v.f = f;
  unsigned r = v.u + 0x7FFF + ((v.u >> 16) & 1);   // round to nearest even
  return r >> 16;
}
static __device__ __forceinline__ float bflo(unsigned u) {  // low bf16 of pair
  return __uint_as_float(u << 16);
}
static __device__ __forceinline__ float bfhi(unsigned u) {  // high bf16 of pair
  return __uint_as_float(u & 0xFFFF0000u);
}

// ---------------- CSR build ----------------

__global__ __launch_bounds__(256) void k_hist(const int* __restrict__ dst,
                                              int* __restrict__ cnt, int E) {
  int i = blockIdx.x * 256 + threadIdx.x;
  if (i < E) atomicAdd(&cnt[dst[i]], 1);
}

__global__ __launch_bounds__(256) void k_dinv(const int* __restrict__ cnt,
                                              float* __restrict__ dinv, int n) {
  int i = blockIdx.x * 256 + threadIdx.x;
  if (i < n) dinv[i] = rsqrtf((float)cnt[i] + 1.0f);
}

__global__ __launch_bounds__(256) void k_scan1(const int* __restrict__ cnt,
                                               int* __restrict__ csum, int n) {
  __shared__ int sm[256];
  int b = blockIdx.x, t = threadIdx.x;
  int base = b * 1024, s = 0;
  for (int i = t; i < 1024; i += 256) {
    int idx = base + i;
    s += (idx < n) ? cnt[idx] : 0;
  }
  sm[t] = s;
  __syncthreads();
  for (int off = 128; off > 0; off >>= 1) {
    if (t < off) sm[t] += sm[t + off];
    __syncthreads();
  }
  if (t == 0) csum[b] = sm[0];
}

__global__ __launch_bounds__(64) void k_scan2(int* __restrict__ csum, int nch) {
  int lane = threadIdx.x & 63;
  if (nch <= 64) {
    int orig = (lane < nch) ? csum[lane] : 0;
    int v = orig;
    for (int off = 1; off < 64; off <<= 1) {
      int y = __shfl_up(v, off);
      if (lane >= off) v += y;
    }
    if (lane < nch) csum[lane] = v - orig;
  } else if (lane == 0) {
    int run = 0;
    for (int i = 0; i < nch; ++i) { int v = csum[i]; csum[i] = run; run += v; }
  }
}

__global__ __launch_bounds__(256) void k_scan3(const int* __restrict__ cnt,
                                               const int* __restrict__ csum,
                                               int* __restrict__ rowptr,
                                               int n, int E) {
  __shared__ int sm[256];
  int b = blockIdx.x, t = threadIdx.x;
  int base = b * 1024;
  int v[4], loc = 0;
#pragma unroll
  for (int k = 0; k < 4; ++k) {
    int idx = base + t * 4 + k;
    v[k] = (idx < n) ? cnt[idx] : 0;
    loc += v[k];
  }
  sm[t] = loc;
  __syncthreads();
  for (int off = 1; off < 256; off <<= 1) {
    int y = (t >= off) ? sm[t - off] : 0;
    __syncthreads();
    sm[t] += y;
    __syncthreads();
  }
  int run = csum[b] + sm[t] - loc;
#pragma unroll
  for (int k = 0; k < 4; ++k) {
    int idx = base + t * 4 + k;
    if (idx < n) { rowptr[idx] = run; run += v[k]; }
  }
  if (b == 0 && t == 0) rowptr[n] = E;
}

__global__ __launch_bounds__(256) void k_binit(const int* __restrict__ rowptr,
                                               int* __restrict__ bCursor, int nb) {
  int b = blockIdx.x * 256 + threadIdx.x;
  if (b < nb) bCursor[b] = rowptr[b << BK_SHIFT];
}

__global__ __launch_bounds__(256) void k_bucketA(const int* __restrict__ src,
                                                 const int* __restrict__ dst,
                                                 int* __restrict__ bCursor,
                                                 int* __restrict__ packed,
                                                 int E, int nb) {
  __shared__ int hist[NBMAX];
  __shared__ int base[NBMAX];
  int t = threadIdx.x;
  int e0 = blockIdx.x * TILE_A;

  for (int b = t; b < nb; b += 256) hist[b] = 0;
  __syncthreads();

  for (int i = t; i < TILE_A; i += 256) {
    int e = e0 + i;
    if (e < E) atomicAdd(&hist[dst[e] >> BK_SHIFT], 1);
  }
  __syncthreads();

  for (int b = t; b < nb; b += 256) {
    int h = hist[b];
    if (h) base[b] = atomicAdd(&bCursor[b], h);
  }
  __syncthreads();

  for (int i = t; i < TILE_A; i += 256) {
    int e = e0 + i;
    if (e < E) {
      int d = dst[e];
      int bkt = d >> BK_SHIFT;
      int pos = atomicAdd(&base[bkt], 1);
      packed[pos] = (src[e] & 0xFFFF) | ((d & (BK_NODES - 1)) << 16);
    }
  }
}

__global__ __launch_bounds__(512) void k_bucketB(const int* __restrict__ packed,
                                                 const int* __restrict__ rowptr,
                                                 int* __restrict__ srcSorted,
                                                 int n) {
  __shared__ int hist[BK_NODES];
  __shared__ int buf[BUFCAP];
  int t = threadIdx.x;
  int bkt = blockIdx.x;
  int n0 = bkt << BK_SHIFT;
  int n1 = n0 + BK_NODES; if (n1 > n) n1 = n;
  int beg = rowptr[n0], end = rowptr[n1];
  int cnt = end - beg;

  if (t < BK_NODES) hist[t] = 0;
  __syncthreads();

  for (int i = t; i < cnt; i += 512)
    atomicAdd(&hist[packed[beg + i] >> 16], 1);
  __syncthreads();

  if (t == 0) {
    int run = 0;
#pragma unroll
    for (int j = 0; j < BK_NODES; ++j) { int v = hist[j]; hist[j] = run; run += v; }
  }
  __syncthreads();

  if (cnt <= BUFCAP) {
    for (int i = t; i < cnt; i += 512) {
      int p = packed[beg + i];
      int pos = atomicAdd(&hist[p >> 16], 1);
      buf[pos] = p & 0xFFFF;
    }
    __syncthreads();
    for (int i = t; i < cnt; i += 512) srcSorted[beg + i] = buf[i];
  } else {
    for (int i = t; i < cnt; i += 512) {
      int p = packed[beg + i];
      int pos = atomicAdd(&hist[p >> 16], 1);
      srcSorted[beg + pos] = p & 0xFFFF;
    }
  }
}

// ---------------- aggregation (CSR, wave per node, bf16 gather) -------------
// EPI=0: out = agg (f32).  EPI=1: out = bf16( relu((agg + bias) * mask) ).

template <int EPI>
__global__ __launch_bounds__(256) void k_aggb(const unsigned* __restrict__ Hb,
                                              const int* __restrict__ srcSorted,
                                              const int* __restrict__ rowptr,
                                              const float* __restrict__ dinv,
                                              const float* __restrict__ bias,
                                              const float* __restrict__ mask,
                                              float* __restrict__ outF,
                                              unsigned* __restrict__ outB,
                                              int n) {
  int wave = (blockIdx.x * 256 + threadIdx.x) >> 6;
  int lane = threadIdx.x & 63;
  if (wave >= n) return;
  int beg = rowptr[wave], end = rowptr[wave + 1];
  float ax = 0.f, ay = 0.f;
  int j = beg;
  for (; j + 3 < end; j += 4) {
    int s0 = srcSorted[j], s1 = srcSorted[j + 1];
    int s2 = srcSorted[j + 2], s3 = srcSorted[j + 3];
    float w0 = dinv[s0], w1 = dinv[s1], w2 = dinv[s2], w3 = dinv[s3];
    unsigned u0 = Hb[(size_t)s0 * 64 + lane];
    unsigned u1 = Hb[(size_t)s1 * 64 + lane];
    unsigned u2 = Hb[(size_t)s2 * 64 + lane];
    unsigned u3 = Hb[(size_t)s3 * 64 + lane];
    ax += bflo(u0) * w0 + bflo(u1) * w1 + bflo(u2) * w2 + bflo(u3) * w3;
    ay += bfhi(u0) * w0 + bfhi(u1) * w1 + bfhi(u2) * w2 + bfhi(u3) * w3;
  }
  for (; j < end; ++j) {
    int s = srcSorted[j];
    float w = dinv[s];
    unsigned u = Hb[(size_t)s * 64 + lane];
    ax += bflo(u) * w;
    ay += bfhi(u) * w;
  }
  float dn = dinv[wave];
  unsigned us = Hb[(size_t)wave * 64 + lane];
  float ox = ax * dn + bflo(us) * dn * dn;
  float oy = ay * dn + bfhi(us) * dn * dn;
  if (EPI == 1) {
    float2 bv = ((const float2*)bias)[lane];
    float2 mv = ((const float2*)mask)[(size_t)wave * 64 + lane];
    float hx = fmaxf((ox + bv.x) * mv.x, 0.f);
    float hy = fmaxf((oy + bv.y) * mv.y, 0.f);
    outB[(size_t)wave * 64 + lane] = f2bf(hx) | (f2bf(hy) << 16);
  } else {
    ((float2*)outF)[(size_t)wave * 64 + lane] = make_float2(ox, oy);
  }
}

// ---------------- GEMM: C = X @ W^T (+ b), f32 or bf16 out ------------------

template <bool BF16OUT>
__global__ __launch_bounds__(256) void k_gemm128(const float* __restrict__ X,
                                                 const float* __restrict__ W,
                                                 const float* __restrict__ bias,
                                                 float* __restrict__ Cf,
                                                 unsigned short* __restrict__ Cb,
                                                 int nrows) {
  __shared__ float Xs[64][132];
  __shared__ float Ws[32][128];

  int tid = threadIdx.x;
  int row0 = blockIdx.x * 64;

  for (int t = tid; t < 2048; t += 256) {
    int r = t >> 5;
    int c4 = (t & 31) << 2;
    int gr = row0 + r;
    float4 v = make_float4(0.f, 0.f, 0.f, 0.f);
    if (gr < nrows) v = *(const float4*)(X + (size_t)gr * D + c4);
    Xs[r][c4 + 0] = v.x; Xs[r][c4 + 1] = v.y;
    Xs[r][c4 + 2] = v.z; Xs[r][c4 + 3] = v.w;
  }

  float acc[4][8];
#pragma unroll
  for (int i = 0; i < 4; ++i)
#pragma unroll
    for (int j = 0; j < 8; ++j) acc[i][j] = 0.f;

  int ty = tid >> 4, tx = tid & 15;
  int r0 = ty << 2, c0 = tx << 3;

  for (int k0 = 0; k0 < 128; k0 += 32) {
    int j = tid >> 1;
    int kkb = (tid & 1) << 4;
    const float4* wp = (const float4*)(W + j * D + k0 + kkb);
    float4 wa = wp[0], wb = wp[1], wc = wp[2], wd = wp[3];

    __syncthreads();
    Ws[kkb +  0][j] = wa.x; Ws[kkb +  1][j] = wa.y; Ws[kkb +  2][j] = wa.z; Ws[kkb +  3][j] = wa.w;
    Ws[kkb +  4][j] = wb.x; Ws[kkb +  5][j] = wb.y; Ws[kkb +  6][j] = wb.z; Ws[kkb +  7][j] = wb.w;
    Ws[kkb +  8][j] = wc.x; Ws[kkb +  9][j] = wc.y; Ws[kkb + 10][j] = wc.z; Ws[kkb + 11][j] = wc.w;
    Ws[kkb + 12][j] = wd.x; Ws[kkb + 13][j] = wd.y; Ws[kkb + 14][j] = wd.z; Ws[kkb + 15][j] = wd.w;
    __syncthreads();

#pragma unroll
    for (int kk = 0; kk < 32; ++kk) {
      float xi[4];
      xi[0] = Xs[r0 + 0][k0 + kk];
      xi[1] = Xs[r0 + 1][k0 + kk];
      xi[2] = Xs[r0 + 2][k0 + kk];
      xi[3] = Xs[r0 + 3][k0 + kk];
      float4 wv0 = *(const float4*)(&Ws[kk][c0]);
      float4 wv1 = *(const float4*)(&Ws[kk][c0 + 4]);
      float wf[8] = {wv0.x, wv0.y, wv0.z, wv0.w, wv1.x, wv1.y, wv1.z, wv1.w};
#pragma unroll
      for (int i = 0; i < 4; ++i)
#pragma unroll
        for (int jj = 0; jj < 8; ++jj) acc[i][jj] += xi[i] * wf[jj];
    }
  }

  float4 bv0 = make_float4(0.f, 0.f, 0.f, 0.f);
  float4 bv1 = make_float4(0.f, 0.f, 0.f, 0.f);
  if (bias) {
    bv0 = *(const float4*)(bias + c0);
    bv1 = *(const float4*)(bias + c0 + 4);
  }

#pragma unroll
  for (int i = 0; i < 4; ++i) {
    int gr = row0 + r0 + i;
    if (gr < nrows) {
      float o[8];
      o[0] = acc[i][0] + bv0.x; o[1] = acc[i][1] + bv0.y;
      o[2] = acc[i][2] + bv0.z; o[3] = acc[i][3] + bv0.w;
      o[4] = acc[i][4] + bv1.x; o[5] = acc[i][5] + bv1.y;
      o[6] = acc[i][6] + bv1.z; o[7] = acc[i][7] + bv1.w;
      if (BF16OUT) {
        uint4 pk;
        pk.x = f2bf(o[0]) | (f2bf(o[1]) << 16);
        pk.y = f2bf(o[2]) | (f2bf(o[3]) << 16);
        pk.z = f2bf(o[4]) | (f2bf(o[5]) << 16);
        pk.w = f2bf(o[6]) | (f2bf(o[7]) << 16);
        *(uint4*)(Cb + (size_t)gr * D + c0) = pk;
      } else {
        *(float4*)(Cf + (size_t)gr * D + c0)     = make_float4(o[0], o[1], o[2], o[3]);
        *(float4*)(Cf + (size_t)gr * D + c0 + 4) = make_float4(o[4], o[5], o[6], o[7]);
      }
    }
  }
}

// ---------------- atomic fallback helpers (round-2 path) --------------------

__global__ __launch_bounds__(256) void k_deg_f(const int* __restrict__ dst,
                                               float* __restrict__ deg, int E) {
  int i = blockIdx.x * 256 + threadIdx.x;
  if (i < E) atomicAdd(&deg[dst[i]], 1.0f);
}

__global__ __launch_bounds__(256) void k_dinv_f(float* __restrict__ deg, int n) {
  int i = blockIdx.x * 256 + threadIdx.x;
  if (i < n) deg[i] = rsqrtf(deg[i] + 1.0f);
}

__global__ __launch_bounds__(256) void k_selfmul(const float* __restrict__ X,
                                                 const float* __restrict__ dinv,
                                                 float* __restrict__ out, int n) {
  int i = blockIdx.x * 256 + threadIdx.x;
  if (i >= n * 32) return;
  int r = i >> 5, c4 = (i & 31) << 2;
  float di = dinv[r];
  float s = di * di;
  float4 h = *(const float4*)(X + (size_t)r * D + c4);
  h.x *= s; h.y *= s; h.z *= s; h.w *= s;
  *(float4*)(out + (size_t)r * D + c4) = h;
}

__global__ __launch_bounds__(256) void k_relumask(float* __restrict__ h,
                                                  const float* __restrict__ mask, int n) {
  int i = blockIdx.x * 256 + threadIdx.x;
  if (i >= n * 32) return;
  float4 v = *(const float4*)(h + (size_t)i * 4);
  float4 m = *(const float4*)(mask + (size_t)i * 4);
  v.x = fmaxf(v.x * m.x, 0.f);
  v.y = fmaxf(v.y * m.y, 0.f);
  v.z = fmaxf(v.z * m.z, 0.f);
  v.w = fmaxf(v.w * m.w, 0.f);
  *(float4*)(h + (size_t)i * 4) = v;
}

__global__ __launch_bounds__(256) void k_aggatomic(const float* __restrict__ X,
                                                   const int* __restrict__ src,
                                                   const int* __restrict__ dst,
                                                   const float* __restrict__ dinv,
                                                   float* __restrict__ out, int E) {
  int gid = blockIdx.x * 256 + threadIdx.x;
  int wave = gid >> 6;
  int lane = threadIdx.x & 63;
  int nw = (gridDim.x * 256) >> 6;
  for (int e = wave; e < E; e += nw) {
    int s = src[e], d = dst[e];
    float nrm = dinv[s] * dinv[d];
    float2 v = ((const float2*)(X + (size_t)s * D))[lane];
    float* op = out + (size_t)d * D + lane * 2;
    atomicAdd(op, v.x * nrm);
    atomicAdd(op + 1, v.y * nrm);
  }
}

__global__ __launch_bounds__(256) void k_addbias(float* __restrict__ C,
                                                 const float* __restrict__ bias, int n) {
  int i = blockIdx.x * 256 + threadIdx.x;
  if (i >= n * 32) return;
  int c4 = (i & 31) << 2;
  float4 v = *(const float4*)(C + (size_t)i * 4);
  float4 b = *(const float4*)(bias + c4);
  v.x += b.x; v.y += b.y; v.z += b.z; v.w += b.w;
  *(float4*)(C + (size_t)i * 4) = v;
}

// ---------------- launch ----------------

extern "C" void kernel_launch(void* const* d_in, const int* in_sizes, int n_in,
                              void* d_out, int out_size, void* d_ws, size_t ws_size,
                              hipStream_t stream) {
  const float* x    = (const float*)d_in[0];
  const int*   ei   = (const int*)d_in[1];
  const float* mask = (const float*)d_in[2];
  const float* W0   = (const float*)d_in[3];
  const float* b0   = (const float*)d_in[4];
  const float* W1   = (const float*)d_in[5];
  const float* b1   = (const float*)d_in[6];
  const float* W2   = (const float*)d_in[7];
  const float* b2   = (const float*)d_in[8];

  const int N = in_sizes[0] / D;
  const int E = in_sizes[1] / 2;
  const int* srcv = ei;
  const int* dstv = ei + E;

  float* out  = (float*)d_out;
  float* outA = out;                    // x_
  float* outB = out + (size_t)N * D;    // x2

  const size_t featBytes  = (size_t)N * D * sizeof(float);   // 25.6 MB
  const size_t featBytesH = (size_t)N * D * sizeof(short);   // 12.8 MB
  const int gGemm  = (N + 63) / 64;
  const int gEdge  = (E + 255) / 256;
  const int gNode  = (N + 255) / 256;
  const int gWaveN = (N + 3) / 4;
  const int gElem  = (N * 32 + 255) / 256;
  const int nch    = (N + 1023) / 1024;
  const int nb     = (N + BK_NODES - 1) >> BK_SHIFT;
  const int gBA    = (E + TILE_A - 1) / TILE_A;

  // compact cumulative workspace layout (256 B aligned)
  auto align256 = [](size_t v) { return (v + 255) & ~(size_t)255; };
  char* w = (char*)d_ws;
  size_t off = 0;
  int*   cnt       = (int*)(w + off);  off = align256(off + (size_t)N * 4);
  float* dinv      = (float*)(w + off); off = align256(off + (size_t)N * 4);
  int*   rowptr    = (int*)(w + off);  off = align256(off + ((size_t)N + 1) * 4);
  int*   csum      = (int*)(w + off);  off = align256(off + 64 * 4);
  int*   bCursor   = (int*)(w + off);  off = align256(off + NBMAX * 4);
  int*   srcSorted = (int*)(w + off);  off = align256(off + (size_t)E * 4);
  float* g         = (float*)(w + off); off = align256(off + featBytes);
  int*   packed    = (int*)g;          // aliases g: consumed by bucketB before g written
  unsigned* h0bf   = (unsigned*)(w + off); off = align256(off + featBytesH);
  unsigned* hbf    = (unsigned*)(w + off); off = align256(off + featBytesH);
  size_t need = off;

  if (ws_size >= need && N <= 65536 && nb <= NBMAX &&
      (size_t)E * sizeof(int) <= featBytes) {
    // ---- CSR build ----
    hipMemsetAsync(cnt, 0, (size_t)N * sizeof(int), stream);
    k_hist<<<gEdge, 256, 0, stream>>>(dstv, cnt, E);
    k_dinv<<<gNode, 256, 0, stream>>>(cnt, dinv, N);
    k_scan1<<<nch, 256, 0, stream>>>(cnt, csum, N);
    k_scan2<<<1, 64, 0, stream>>>(csum, nch);
    k_scan3<<<nch, 256, 0, stream>>>(cnt, csum, rowptr, N, E);
    k_binit<<<(nb + 255) / 256, 256, 0, stream>>>(rowptr, bCursor, nb);
    k_bucketA<<<gBA, 256, 0, stream>>>(srcv, dstv, bCursor, packed, E, nb);
    k_bucketB<<<nb, 512, 0, stream>>>(packed, rowptr, srcSorted, N);

    // layer 0 (GEMM-first): h0 = x @ W0^T  (bf16)
    k_gemm128<true><<<gGemm, 256, 0, stream>>>(x, W0, nullptr, nullptr,
                                               (unsigned short*)h0bf, N);
    // h = bf16( relu((agg(h0) + b0) * mask) )
    k_aggb<1><<<gWaveN, 256, 0, stream>>>(h0bf, srcSorted, rowptr, dinv,
                                          b0, mask, nullptr, hbf, N);
    // g = agg(h)  (f32)
    k_aggb<0><<<gWaveN, 256, 0, stream>>>(hbf, srcSorted, rowptr, dinv,
                                          nullptr, nullptr, g, nullptr, N);
    // x_ = g @ W1^T + b1 ; x2 = g @ W2^T + b2
    k_gemm128<false><<<gGemm, 256, 0, stream>>>(g, W1, b1, outA, nullptr, N);
    k_gemm128<false><<<gGemm, 256, 0, stream>>>(g, W2, b2, outB, nullptr, N);
  } else {
    // ---- atomic fallback (commuted, 2 aggs, all f32) ----
    float* fdinv = (float*)(w);
    float* fA    = (float*)(w + 0x40000);
    float* fB    = (float*)((char*)fA + featBytes);
    hipMemsetAsync(fdinv, 0, (size_t)N * sizeof(float), stream);
    k_deg_f<<<gEdge, 256, 0, stream>>>(dstv, fdinv, E);
    k_dinv_f<<<gNode, 256, 0, stream>>>(fdinv, N);
    // h0 = x @ W0^T (f32), then out0 = agg(h0) + b0, h = relu(out0*mask)
    k_gemm128<false><<<gGemm, 256, 0, stream>>>(x, W0, nullptr, fB, nullptr, N);
    k_selfmul<<<gElem, 256, 0, stream>>>(fB, fdinv, fA, N);
    k_aggatomic<<<4096, 256, 0, stream>>>(fB, srcv, dstv, fdinv, fA, E);
    k_addbias<<<gElem, 256, 0, stream>>>(fA, b0, N);
    k_relumask<<<gElem, 256, 0, stream>>>(fA, mask, N);
    // g = agg(h)
    k_selfmul<<<gElem, 256, 0, stream>>>(fA, fdinv, fB, N);
    k_aggatomic<<<4096, 256, 0, stream>>>(fA, srcv, dstv, fdinv, fB, E);
    k_gemm128<false><<<gGemm, 256, 0, stream>>>(fB, W1, b1, outA, nullptr, N);
    k_gemm128<false><<<gGemm, 256, 0, stream>>>(fB, W2, b2, outB, nullptr, N);
  }
}

// Round 8
// 289.114 us; speedup vs baseline: 14.3312x; 1.2706x over previous
//
#include <hip/hip_runtime.h>

// ---------------------------------------------------------------------------
// GCN encoder, N=50000, E=1.6M, D=128.
// Round 8: (a) pre-scaled bf16 gather tables t[s]=dinv[s]*h[s] -> agg inner
// loop is load+add only (no dinv gather, no weight FMA), unroll 8;
// (b) CSR build collapsed: coarse 391-bin hist + 1 scan + bucketA + bucketB2
// (bucketB2 emits rowptr, dinv, sorted edges from its LDS histogram).
// ---------------------------------------------------------------------------

#define D 128
#define BK_SHIFT 7            // 128 nodes per bucket
#define BK_NODES 128
#define NBMAX 512             // max buckets (N <= 65536); also cscan width
#define BUFCAP 6144           // LDS staging capacity (edges) in k_bucketB2
#define TILE_A 2048           // edges per block in k_bucketA
#define TILE_CH 4096          // edges per block in k_chist

static __device__ __forceinline__ unsigned f2bf(float f) {
  union { float f; unsigned u; } v; v.f = f;
  unsigned r = v.u + 0x7FFF + ((v.u >> 16) & 1);   // round to nearest even
  return r >> 16;
}
static __device__ __forceinline__ float bflo(unsigned u) {
  return __uint_as_float(u << 16);
}
static __device__ __forceinline__ float bfhi(unsigned u) {
  return __uint_as_float(u & 0xFFFF0000u);
}

// ---------------- CSR build ----------------

// coarse histogram over buckets (dst >> BK_SHIFT)
__global__ __launch_bounds__(256) void k_chist(const int* __restrict__ dst,
                                               int* __restrict__ coarse,
                                               int E, int nb) {
  __shared__ int bins[NBMAX];
  int t = threadIdx.x;
  int e0 = blockIdx.x * TILE_CH;
  for (int b = t; b < nb; b += 256) bins[b] = 0;
  __syncthreads();
  for (int i = t; i < TILE_CH; i += 256) {
    int e = e0 + i;
    if (e < E) atomicAdd(&bins[dst[e] >> BK_SHIFT], 1);
  }
  __syncthreads();
  for (int b = t; b < nb; b += 256) {
    int v = bins[b];
    if (v) atomicAdd(&coarse[b], v);
  }
}

// exclusive scan of nb (<=512) coarse counts -> cbase[0..nb], bCursor copy
__global__ __launch_bounds__(NBMAX) void k_cscan(const int* __restrict__ coarse,
                                                 int* __restrict__ cbase,
                                                 int* __restrict__ bCursor,
                                                 int nb, int E) {
  __shared__ int sm[NBMAX];
  int t = threadIdx.x;
  int v = (t < nb) ? coarse[t] : 0;
  sm[t] = v;
  __syncthreads();
  for (int off = 1; off < NBMAX; off <<= 1) {
    int y = (t >= off) ? sm[t - off] : 0;
    __syncthreads();
    sm[t] += y;
    __syncthreads();
  }
  int excl = sm[t] - v;
  if (t < nb) { cbase[t] = excl; bCursor[t] = excl; }
  if (t == 0) cbase[nb] = E;
}

// Phase A: bucket edges into bucket-contiguous runs of packed (dstoff<<16|src)
__global__ __launch_bounds__(256) void k_bucketA(const int* __restrict__ src,
                                                 const int* __restrict__ dst,
                                                 int* __restrict__ bCursor,
                                                 int* __restrict__ packed,
                                                 int E, int nb) {
  __shared__ int hist[NBMAX];
  __shared__ int base[NBMAX];
  int t = threadIdx.x;
  int e0 = blockIdx.x * TILE_A;

  for (int b = t; b < nb; b += 256) hist[b] = 0;
  __syncthreads();

  for (int i = t; i < TILE_A; i += 256) {
    int e = e0 + i;
    if (e < E) atomicAdd(&hist[dst[e] >> BK_SHIFT], 1);
  }
  __syncthreads();

  for (int b = t; b < nb; b += 256) {
    int h = hist[b];
    if (h) base[b] = atomicAdd(&bCursor[b], h);
  }
  __syncthreads();

  for (int i = t; i < TILE_A; i += 256) {
    int e = e0 + i;
    if (e < E) {
      int d = dst[e];
      int bkt = d >> BK_SHIFT;
      int pos = atomicAdd(&base[bkt], 1);
      packed[pos] = (src[e] & 0xFFFF) | ((d & (BK_NODES - 1)) << 16);
    }
  }
}

// Phase B: per bucket, node-level LDS histogram -> rowptr + dinv + sorted srcs
__global__ __launch_bounds__(512) void k_bucketB2(const int* __restrict__ packed,
                                                  const int* __restrict__ cbase,
                                                  int* __restrict__ srcSorted,
                                                  int* __restrict__ rowptr,
                                                  float* __restrict__ dinv,
                                                  int n, int E) {
  __shared__ int histC[BK_NODES];
  __shared__ int cur[BK_NODES];
  __shared__ int buf[BUFCAP];
  int t = threadIdx.x;
  int bkt = blockIdx.x;
  int n0 = bkt << BK_SHIFT;
  int beg = cbase[bkt], end = cbase[bkt + 1];
  int cnt = end - beg;

  if (t < BK_NODES) histC[t] = 0;
  __syncthreads();

  for (int i = t; i < cnt; i += 512)
    atomicAdd(&histC[packed[beg + i] >> 16], 1);
  __syncthreads();

  if (t == 0) {
    int run = 0;
#pragma unroll
    for (int j = 0; j < BK_NODES; ++j) { cur[j] = run; run += histC[j]; }
  }
  __syncthreads();

  if (t < BK_NODES && n0 + t < n) {
    rowptr[n0 + t] = beg + cur[t];
    dinv[n0 + t]   = rsqrtf((float)histC[t] + 1.0f);
  }
  if (bkt == (int)gridDim.x - 1 && t == 0) rowptr[n] = E;
  __syncthreads();   // rowptr writes read cur before scatter mutates it

  if (cnt <= BUFCAP) {
    for (int i = t; i < cnt; i += 512) {
      int p = packed[beg + i];
      int pos = atomicAdd(&cur[p >> 16], 1);
      buf[pos] = p & 0xFFFF;
    }
    __syncthreads();
    for (int i = t; i < cnt; i += 512) srcSorted[beg + i] = buf[i];
  } else {           // correctness fallback, never expected
    for (int i = t; i < cnt; i += 512) {
      int p = packed[beg + i];
      int pos = atomicAdd(&cur[p >> 16], 1);
      srcSorted[beg + pos] = p & 0xFFFF;
    }
  }
}

// ------------- aggregation (wave/node; pre-scaled bf16 table) ---------------
// T[s] holds bf16(dinv[s]*h[s]) packed 2/word. out[d] = dinv[d]*(T[d]+sum T[s]).
// EPI=0: outF = that (f32).
// EPI=1: h = relu((that + bias)*mask); outB = bf16(dinv[d]*h)  (next table).

template <int EPI>
__global__ __launch_bounds__(256) void k_aggb(const unsigned* __restrict__ T,
                                              const int* __restrict__ srcSorted,
                                              const int* __restrict__ rowptr,
                                              const float* __restrict__ dinv,
                                              const float* __restrict__ bias,
                                              const float* __restrict__ mask,
                                              float* __restrict__ outF,
                                              unsigned* __restrict__ outB,
                                              int n) {
  int wave = (blockIdx.x * 256 + threadIdx.x) >> 6;
  int lane = threadIdx.x & 63;
  if (wave >= n) return;
  int beg = rowptr[wave], end = rowptr[wave + 1];
  float ax = 0.f, ay = 0.f, bx = 0.f, by = 0.f;
  int j = beg;
  for (; j + 7 < end; j += 8) {
    int s0 = srcSorted[j],     s1 = srcSorted[j + 1];
    int s2 = srcSorted[j + 2], s3 = srcSorted[j + 3];
    int s4 = srcSorted[j + 4], s5 = srcSorted[j + 5];
    int s6 = srcSorted[j + 6], s7 = srcSorted[j + 7];
    unsigned u0 = T[(size_t)s0 * 64 + lane];
    unsigned u1 = T[(size_t)s1 * 64 + lane];
    unsigned u2 = T[(size_t)s2 * 64 + lane];
    unsigned u3 = T[(size_t)s3 * 64 + lane];
    unsigned u4 = T[(size_t)s4 * 64 + lane];
    unsigned u5 = T[(size_t)s5 * 64 + lane];
    unsigned u6 = T[(size_t)s6 * 64 + lane];
    unsigned u7 = T[(size_t)s7 * 64 + lane];
    ax += bflo(u0) + bflo(u2);  bx += bflo(u1) + bflo(u3);
    ay += bfhi(u0) + bfhi(u2);  by += bfhi(u1) + bfhi(u3);
    ax += bflo(u4) + bflo(u6);  bx += bflo(u5) + bflo(u7);
    ay += bfhi(u4) + bfhi(u6);  by += bfhi(u5) + bfhi(u7);
  }
  for (; j < end; ++j) {
    int s = srcSorted[j];
    unsigned u = T[(size_t)s * 64 + lane];
    ax += bflo(u);
    ay += bfhi(u);
  }
  unsigned us = T[(size_t)wave * 64 + lane];   // self term
  float dn = dinv[wave];
  float ox = (ax + bx + bflo(us)) * dn;
  float oy = (ay + by + bfhi(us)) * dn;
  if (EPI == 1) {
    float2 bv = ((const float2*)bias)[lane];
    float2 mv = ((const float2*)mask)[(size_t)wave * 64 + lane];
    float hx = fmaxf((ox + bv.x) * mv.x, 0.f);
    float hy = fmaxf((oy + bv.y) * mv.y, 0.f);
    outB[(size_t)wave * 64 + lane] = f2bf(hx * dn) | (f2bf(hy * dn) << 16);
  } else {
    ((float2*)outF)[(size_t)wave * 64 + lane] = make_float2(ox, oy);
  }
}

// ------------- GEMM: C = X @ W^T (+b); bf16-out path scales by prescale -----

template <bool BF16OUT>
__global__ __launch_bounds__(256) void k_gemm128(const float* __restrict__ X,
                                                 const float* __restrict__ W,
                                                 const float* __restrict__ bias,
                                                 const float* __restrict__ prescale,
                                                 float* __restrict__ Cf,
                                                 unsigned short* __restrict__ Cb,
                                                 int nrows) {
  __shared__ float Xs[64][132];
  __shared__ float Ws[32][128];

  int tid = threadIdx.x;
  int row0 = blockIdx.x * 64;

  for (int t = tid; t < 2048; t += 256) {
    int r = t >> 5;
    int c4 = (t & 31) << 2;
    int gr = row0 + r;
    float4 v = make_float4(0.f, 0.f, 0.f, 0.f);
    if (gr < nrows) v = *(const float4*)(X + (size_t)gr * D + c4);
    Xs[r][c4 + 0] = v.x; Xs[r][c4 + 1] = v.y;
    Xs[r][c4 + 2] = v.z; Xs[r][c4 + 3] = v.w;
  }

  float acc[4][8];
#pragma unroll
  for (int i = 0; i < 4; ++i)
#pragma unroll
    for (int j = 0; j < 8; ++j) acc[i][j] = 0.f;

  int ty = tid >> 4, tx = tid & 15;
  int r0 = ty << 2, c0 = tx << 3;

  for (int k0 = 0; k0 < 128; k0 += 32) {
    int j = tid >> 1;
    int kkb = (tid & 1) << 4;
    const float4* wp = (const float4*)(W + j * D + k0 + kkb);
    float4 wa = wp[0], wb = wp[1], wc = wp[2], wd = wp[3];

    __syncthreads();
    Ws[kkb +  0][j] = wa.x; Ws[kkb +  1][j] = wa.y; Ws[kkb +  2][j] = wa.z; Ws[kkb +  3][j] = wa.w;
    Ws[kkb +  4][j] = wb.x; Ws[kkb +  5][j] = wb.y; Ws[kkb +  6][j] = wb.z; Ws[kkb +  7][j] = wb.w;
    Ws[kkb +  8][j] = wc.x; Ws[kkb +  9][j] = wc.y; Ws[kkb + 10][j] = wc.z; Ws[kkb + 11][j] = wc.w;
    Ws[kkb + 12][j] = wd.x; Ws[kkb + 13][j] = wd.y; Ws[kkb + 14][j] = wd.z; Ws[kkb + 15][j] = wd.w;
    __syncthreads();

#pragma unroll
    for (int kk = 0; kk < 32; ++kk) {
      float xi[4];
      xi[0] = Xs[r0 + 0][k0 + kk];
      xi[1] = Xs[r0 + 1][k0 + kk];
      xi[2] = Xs[r0 + 2][k0 + kk];
      xi[3] = Xs[r0 + 3][k0 + kk];
      float4 wv0 = *(const float4*)(&Ws[kk][c0]);
      float4 wv1 = *(const float4*)(&Ws[kk][c0 + 4]);
      float wf[8] = {wv0.x, wv0.y, wv0.z, wv0.w, wv1.x, wv1.y, wv1.z, wv1.w};
#pragma unroll
      for (int i = 0; i < 4; ++i)
#pragma unroll
        for (int jj = 0; jj < 8; ++jj) acc[i][jj] += xi[i] * wf[jj];
    }
  }

  float4 bv0 = make_float4(0.f, 0.f, 0.f, 0.f);
  float4 bv1 = make_float4(0.f, 0.f, 0.f, 0.f);
  if (bias) {
    bv0 = *(const float4*)(bias + c0);
    bv1 = *(const float4*)(bias + c0 + 4);
  }

#pragma unroll
  for (int i = 0; i < 4; ++i) {
    int gr = row0 + r0 + i;
    if (gr < nrows) {
      float o[8];
      o[0] = acc[i][0] + bv0.x; o[1] = acc[i][1] + bv0.y;
      o[2] = acc[i][2] + bv0.z; o[3] = acc[i][3] + bv0.w;
      o[4] = acc[i][4] + bv1.x; o[5] = acc[i][5] + bv1.y;
      o[6] = acc[i][6] + bv1.z; o[7] = acc[i][7] + bv1.w;
      if (BF16OUT) {
        float dn = prescale ? prescale[gr] : 1.0f;
        uint4 pk;
        pk.x = f2bf(o[0] * dn) | (f2bf(o[1] * dn) << 16);
        pk.y = f2bf(o[2] * dn) | (f2bf(o[3] * dn) << 16);
        pk.z = f2bf(o[4] * dn) | (f2bf(o[5] * dn) << 16);
        pk.w = f2bf(o[6] * dn) | (f2bf(o[7] * dn) << 16);
        *(uint4*)(Cb + (size_t)gr * D + c0) = pk;
      } else {
        *(float4*)(Cf + (size_t)gr * D + c0)     = make_float4(o[0], o[1], o[2], o[3]);
        *(float4*)(Cf + (size_t)gr * D + c0 + 4) = make_float4(o[4], o[5], o[6], o[7]);
      }
    }
  }
}

// ---------------- atomic fallback helpers --------------------

__global__ __launch_bounds__(256) void k_deg_f(const int* __restrict__ dst,
                                               float* __restrict__ deg, int E) {
  int i = blockIdx.x * 256 + threadIdx.x;
  if (i < E) atomicAdd(&deg[dst[i]], 1.0f);
}

__global__ __launch_bounds__(256) void k_dinv_f(float* __restrict__ deg, int n) {
  int i = blockIdx.x * 256 + threadIdx.x;
  if (i < n) deg[i] = rsqrtf(deg[i] + 1.0f);
}

__global__ __launch_bounds__(256) void k_selfmul(const float* __restrict__ X,
                                                 const float* __restrict__ dinv,
                                                 float* __restrict__ out, int n) {
  int i = blockIdx.x * 256 + threadIdx.x;
  if (i >= n * 32) return;
  int r = i >> 5, c4 = (i & 31) << 2;
  float di = dinv[r];
  float s = di * di;
  float4 h = *(const float4*)(X + (size_t)r * D + c4);
  h.x *= s; h.y *= s; h.z *= s; h.w *= s;
  *(float4*)(out + (size_t)r * D + c4) = h;
}

__global__ __launch_bounds__(256) void k_relumask(float* __restrict__ h,
                                                  const float* __restrict__ mask, int n) {
  int i = blockIdx.x * 256 + threadIdx.x;
  if (i >= n * 32) return;
  float4 v = *(const float4*)(h + (size_t)i * 4);
  float4 m = *(const float4*)(mask + (size_t)i * 4);
  v.x = fmaxf(v.x * m.x, 0.f);
  v.y = fmaxf(v.y * m.y, 0.f);
  v.z = fmaxf(v.z * m.z, 0.f);
  v.w = fmaxf(v.w * m.w, 0.f);
  *(float4*)(h + (size_t)i * 4) = v;
}

__global__ __launch_bounds__(256) void k_aggatomic(const float* __restrict__ X,
                                                   const int* __restrict__ src,
                                                   const int* __restrict__ dst,
                                                   const float* __restrict__ dinv,
                                                   float* __restrict__ out, int E) {
  int gid = blockIdx.x * 256 + threadIdx.x;
  int wave = gid >> 6;
  int lane = threadIdx.x & 63;
  int nw = (gridDim.x * 256) >> 6;
  for (int e = wave; e < E; e += nw) {
    int s = src[e], d = dst[e];
    float nrm = dinv[s] * dinv[d];
    float2 v = ((const float2*)(X + (size_t)s * D))[lane];
    float* op = out + (size_t)d * D + lane * 2;
    atomicAdd(op, v.x * nrm);
    atomicAdd(op + 1, v.y * nrm);
  }
}

__global__ __launch_bounds__(256) void k_addbias(float* __restrict__ C,
                                                 const float* __restrict__ bias, int n) {
  int i = blockIdx.x * 256 + threadIdx.x;
  if (i >= n * 32) return;
  int c4 = (i & 31) << 2;
  float4 v = *(const float4*)(C + (size_t)i * 4);
  float4 b = *(const float4*)(bias + c4);
  v.x += b.x; v.y += b.y; v.z += b.z; v.w += b.w;
  *(float4*)(C + (size_t)i * 4) = v;
}

// ---------------- launch ----------------

extern "C" void kernel_launch(void* const* d_in, const int* in_sizes, int n_in,
                              void* d_out, int out_size, void* d_ws, size_t ws_size,
                              hipStream_t stream) {
  const float* x    = (const float*)d_in[0];
  const int*   ei   = (const int*)d_in[1];
  const float* mask = (const float*)d_in[2];
  const float* W0   = (const float*)d_in[3];
  const float* b0   = (const float*)d_in[4];
  const float* W1   = (const float*)d_in[5];
  const float* b1   = (const float*)d_in[6];
  const float* W2   = (const float*)d_in[7];
  const float* b2   = (const float*)d_in[8];

  const int N = in_sizes[0] / D;
  const int E = in_sizes[1] / 2;
  const int* srcv = ei;
  const int* dstv = ei + E;

  float* out  = (float*)d_out;
  float* outA = out;                    // x_
  float* outB = out + (size_t)N * D;    // x2

  const size_t featBytes  = (size_t)N * D * sizeof(float);
  const size_t featBytesH = (size_t)N * D * sizeof(short);
  const int gGemm  = (N + 63) / 64;
  const int gEdge  = (E + 255) / 256;
  const int gNode  = (N + 255) / 256;
  const int gWaveN = (N + 3) / 4;
  const int gElem  = (N * 32 + 255) / 256;
  const int nb     = (N + BK_NODES - 1) >> BK_SHIFT;
  const int gBA    = (E + TILE_A - 1) / TILE_A;
  const int gCH    = (E + TILE_CH - 1) / TILE_CH;

  auto align256 = [](size_t v) { return (v + 255) & ~(size_t)255; };
  char* w = (char*)d_ws;
  size_t off = 0;
  int*   coarse    = (int*)(w + off);   off = align256(off + (NBMAX + 1) * 4);
  int*   cbase     = (int*)(w + off);   off = align256(off + (NBMAX + 1) * 4);
  int*   bCursor   = (int*)(w + off);   off = align256(off + NBMAX * 4);
  int*   rowptr    = (int*)(w + off);   off = align256(off + ((size_t)N + 1) * 4);
  float* dinv      = (float*)(w + off); off = align256(off + (size_t)N * 4);
  int*   srcSorted = (int*)(w + off);   off = align256(off + (size_t)E * 4);
  float* g         = (float*)(w + off); off = align256(off + featBytes);
  int*   packed    = (int*)g;           // aliases g (consumed before g written)
  unsigned* h0bf   = (unsigned*)(w + off); off = align256(off + featBytesH);
  unsigned* hbf    = (unsigned*)(w + off); off = align256(off + featBytesH);
  size_t need = off;

  if (ws_size >= need && N <= 65536 && nb <= NBMAX &&
      (size_t)E * sizeof(int) <= featBytes) {
    // ---- CSR build (3 kernels + tiny memset) ----
    hipMemsetAsync(coarse, 0, (size_t)(nb + 1) * sizeof(int), stream);
    k_chist<<<gCH, 256, 0, stream>>>(dstv, coarse, E, nb);
    k_cscan<<<1, NBMAX, 0, stream>>>(coarse, cbase, bCursor, nb, E);
    k_bucketA<<<gBA, 256, 0, stream>>>(srcv, dstv, bCursor, packed, E, nb);
    k_bucketB2<<<nb, 512, 0, stream>>>(packed, cbase, srcSorted, rowptr,
                                       dinv, N, E);

    // layer 0: t0 = bf16(dinv * (x @ W0^T))
    k_gemm128<true><<<gGemm, 256, 0, stream>>>(x, W0, nullptr, dinv, nullptr,
                                               (unsigned short*)h0bf, N);
    // t1 = bf16(dinv * relu((agg + b0) * mask))
    k_aggb<1><<<gWaveN, 256, 0, stream>>>(h0bf, srcSorted, rowptr, dinv,
                                          b0, mask, nullptr, hbf, N);
    // g = agg (f32)
    k_aggb<0><<<gWaveN, 256, 0, stream>>>(hbf, srcSorted, rowptr, dinv,
                                          nullptr, nullptr, g, nullptr, N);
    // x_ = g @ W1^T + b1 ; x2 = g @ W2^T + b2
    k_gemm128<false><<<gGemm, 256, 0, stream>>>(g, W1, b1, nullptr, outA, nullptr, N);
    k_gemm128<false><<<gGemm, 256, 0, stream>>>(g, W2, b2, nullptr, outB, nullptr, N);
  } else {
    // ---- atomic fallback (commuted, 2 aggs, all f32) ----
    float* fdinv = (float*)(w);
    float* fA    = (float*)(w + 0x40000);
    float* fB    = (float*)((char*)fA + featBytes);
    hipMemsetAsync(fdinv, 0, (size_t)N * sizeof(float), stream);
    k_deg_f<<<gEdge, 256, 0, stream>>>(dstv, fdinv, E);
    k_dinv_f<<<gNode, 256, 0, stream>>>(fdinv, N);
    k_gemm128<false><<<gGemm, 256, 0, stream>>>(x, W0, nullptr, nullptr, fB, nullptr, N);
    k_selfmul<<<gElem, 256, 0, stream>>>(fB, fdinv, fA, N);
    k_aggatomic<<<4096, 256, 0, stream>>>(fB, srcv, dstv, fdinv, fA, E);
    k_addbias<<<gElem, 256, 0, stream>>>(fA, b0, N);
    k_relumask<<<gElem, 256, 0, stream>>>(fA, mask, N);
    k_selfmul<<<gElem, 256, 0, stream>>>(fA, fdinv, fB, N);
    k_aggatomic<<<4096, 256, 0, stream>>>(fA, srcv, dstv, fdinv, fB, E);
    k_gemm128<false><<<gGemm, 256, 0, stream>>>(fB, W1, b1, nullptr, outA, nullptr, N);
    k_gemm128<false><<<gGemm, 256, 0, stream>>>(fB, W2, b2, nullptr, outB, nullptr, N);
  }
}

// Round 9
// 246.529 us; speedup vs baseline: 16.8067x; 1.1727x over previous
//
#include <hip/hip_runtime.h>

// ---------------------------------------------------------------------------
// GCN encoder, N=50000, E=1.6M, D=128.
// Round 9: MFMA bf16 GEMMs (no LDS; A/B fragments are direct 16B global
// loads; W preconverted to bf16). agg#2 emits bf16 table for gemm1/2.
// Agg + CSR build unchanged from round 8.
// ---------------------------------------------------------------------------

#define D 128
#define BK_SHIFT 7            // 128 nodes per bucket
#define BK_NODES 128
#define NBMAX 512             // max buckets (N <= 65536); also cscan width
#define BUFCAP 6144           // LDS staging capacity (edges) in k_bucketB2
#define TILE_A 2048           // edges per block in k_bucketA
#define TILE_CH 4096          // edges per block in k_chist

typedef __attribute__((ext_vector_type(8))) short bf16x8;
typedef __attribute__((ext_vector_type(4))) float f32x4;

static __device__ __forceinline__ unsigned f2bf(float f) {
  union { float f; unsigned u; } v; v.f = f;
  unsigned r = v.u + 0x7FFF + ((v.u >> 16) & 1);   // round to nearest even
  return r >> 16;
}
static __device__ __forceinline__ float bflo(unsigned u) {
  return __uint_as_float(u << 16);
}
static __device__ __forceinline__ float bfhi(unsigned u) {
  return __uint_as_float(u & 0xFFFF0000u);
}

// ---------------- CSR build ----------------

__global__ __launch_bounds__(256) void k_chist(const int* __restrict__ dst,
                                               int* __restrict__ coarse,
                                               int E, int nb) {
  __shared__ int bins[NBMAX];
  int t = threadIdx.x;
  int e0 = blockIdx.x * TILE_CH;
  for (int b = t; b < nb; b += 256) bins[b] = 0;
  __syncthreads();
  for (int i = t; i < TILE_CH; i += 256) {
    int e = e0 + i;
    if (e < E) atomicAdd(&bins[dst[e] >> BK_SHIFT], 1);
  }
  __syncthreads();
  for (int b = t; b < nb; b += 256) {
    int v = bins[b];
    if (v) atomicAdd(&coarse[b], v);
  }
}

__global__ __launch_bounds__(NBMAX) void k_cscan(const int* __restrict__ coarse,
                                                 int* __restrict__ cbase,
                                                 int* __restrict__ bCursor,
                                                 int nb, int E) {
  __shared__ int sm[NBMAX];
  int t = threadIdx.x;
  int v = (t < nb) ? coarse[t] : 0;
  sm[t] = v;
  __syncthreads();
  for (int off = 1; off < NBMAX; off <<= 1) {
    int y = (t >= off) ? sm[t - off] : 0;
    __syncthreads();
    sm[t] += y;
    __syncthreads();
  }
  int excl = sm[t] - v;
  if (t < nb) { cbase[t] = excl; bCursor[t] = excl; }
  if (t == 0) cbase[nb] = E;
}

__global__ __launch_bounds__(256) void k_bucketA(const int* __restrict__ src,
                                                 const int* __restrict__ dst,
                                                 int* __restrict__ bCursor,
                                                 int* __restrict__ packed,
                                                 int E, int nb) {
  __shared__ int hist[NBMAX];
  __shared__ int base[NBMAX];
  int t = threadIdx.x;
  int e0 = blockIdx.x * TILE_A;

  for (int b = t; b < nb; b += 256) hist[b] = 0;
  __syncthreads();

  for (int i = t; i < TILE_A; i += 256) {
    int e = e0 + i;
    if (e < E) atomicAdd(&hist[dst[e] >> BK_SHIFT], 1);
  }
  __syncthreads();

  for (int b = t; b < nb; b += 256) {
    int h = hist[b];
    if (h) base[b] = atomicAdd(&bCursor[b], h);
  }
  __syncthreads();

  for (int i = t; i < TILE_A; i += 256) {
    int e = e0 + i;
    if (e < E) {
      int d = dst[e];
      int bkt = d >> BK_SHIFT;
      int pos = atomicAdd(&base[bkt], 1);
      packed[pos] = (src[e] & 0xFFFF) | ((d & (BK_NODES - 1)) << 16);
    }
  }
}

__global__ __launch_bounds__(512) void k_bucketB2(const int* __restrict__ packed,
                                                  const int* __restrict__ cbase,
                                                  int* __restrict__ srcSorted,
                                                  int* __restrict__ rowptr,
                                                  float* __restrict__ dinv,
                                                  int n, int E) {
  __shared__ int histC[BK_NODES];
  __shared__ int cur[BK_NODES];
  __shared__ int buf[BUFCAP];
  int t = threadIdx.x;
  int bkt = blockIdx.x;
  int n0 = bkt << BK_SHIFT;
  int beg = cbase[bkt], end = cbase[bkt + 1];
  int cnt = end - beg;

  if (t < BK_NODES) histC[t] = 0;
  __syncthreads();

  for (int i = t; i < cnt; i += 512)
    atomicAdd(&histC[packed[beg + i] >> 16], 1);
  __syncthreads();

  if (t == 0) {
    int run = 0;
#pragma unroll
    for (int j = 0; j < BK_NODES; ++j) { cur[j] = run; run += histC[j]; }
  }
  __syncthreads();

  if (t < BK_NODES && n0 + t < n) {
    rowptr[n0 + t] = beg + cur[t];
    dinv[n0 + t]   = rsqrtf((float)histC[t] + 1.0f);
  }
  if (bkt == (int)gridDim.x - 1 && t == 0) rowptr[n] = E;
  __syncthreads();

  if (cnt <= BUFCAP) {
    for (int i = t; i < cnt; i += 512) {
      int p = packed[beg + i];
      int pos = atomicAdd(&cur[p >> 16], 1);
      buf[pos] = p & 0xFFFF;
    }
    __syncthreads();
    for (int i = t; i < cnt; i += 512) srcSorted[beg + i] = buf[i];
  } else {
    for (int i = t; i < cnt; i += 512) {
      int p = packed[beg + i];
      int pos = atomicAdd(&cur[p >> 16], 1);
      srcSorted[beg + pos] = p & 0xFFFF;
    }
  }
}

// ------------- aggregation (wave/node; pre-scaled bf16 table) ---------------
// T[s] = bf16(dinv[s]*h[s]) packed 2/word. ox = dinv[d]*(T[d] + sum T[s]).
// EPI=0: outF = f32.  EPI=1: h=relu((ox+bias)*mask); outB = bf16(dinv*h).
// EPI=2: outB = bf16(ox).

template <int EPI>
__global__ __launch_bounds__(256) void k_aggb(const unsigned* __restrict__ T,
                                              const int* __restrict__ srcSorted,
                                              const int* __restrict__ rowptr,
                                              const float* __restrict__ dinv,
                                              const float* __restrict__ bias,
                                              const float* __restrict__ mask,
                                              float* __restrict__ outF,
                                              unsigned* __restrict__ outB,
                                              int n) {
  int wave = (blockIdx.x * 256 + threadIdx.x) >> 6;
  int lane = threadIdx.x & 63;
  if (wave >= n) return;
  int beg = rowptr[wave], end = rowptr[wave + 1];
  float ax = 0.f, ay = 0.f, bx = 0.f, by = 0.f;
  int j = beg;
  for (; j + 7 < end; j += 8) {
    int s0 = srcSorted[j],     s1 = srcSorted[j + 1];
    int s2 = srcSorted[j + 2], s3 = srcSorted[j + 3];
    int s4 = srcSorted[j + 4], s5 = srcSorted[j + 5];
    int s6 = srcSorted[j + 6], s7 = srcSorted[j + 7];
    unsigned u0 = T[(size_t)s0 * 64 + lane];
    unsigned u1 = T[(size_t)s1 * 64 + lane];
    unsigned u2 = T[(size_t)s2 * 64 + lane];
    unsigned u3 = T[(size_t)s3 * 64 + lane];
    unsigned u4 = T[(size_t)s4 * 64 + lane];
    unsigned u5 = T[(size_t)s5 * 64 + lane];
    unsigned u6 = T[(size_t)s6 * 64 + lane];
    unsigned u7 = T[(size_t)s7 * 64 + lane];
    ax += bflo(u0) + bflo(u2);  bx += bflo(u1) + bflo(u3);
    ay += bfhi(u0) + bfhi(u2);  by += bfhi(u1) + bfhi(u3);
    ax += bflo(u4) + bflo(u6);  bx += bflo(u5) + bflo(u7);
    ay += bfhi(u4) + bfhi(u6);  by += bfhi(u5) + bfhi(u7);
  }
  for (; j < end; ++j) {
    int s = srcSorted[j];
    unsigned u = T[(size_t)s * 64 + lane];
    ax += bflo(u);
    ay += bfhi(u);
  }
  unsigned us = T[(size_t)wave * 64 + lane];   // self term
  float dn = dinv[wave];
  float ox = (ax + bx + bflo(us)) * dn;
  float oy = (ay + by + bfhi(us)) * dn;
  if (EPI == 1) {
    float2 bv = ((const float2*)bias)[lane];
    float2 mv = ((const float2*)mask)[(size_t)wave * 64 + lane];
    float hx = fmaxf((ox + bv.x) * mv.x, 0.f);
    float hy = fmaxf((oy + bv.y) * mv.y, 0.f);
    outB[(size_t)wave * 64 + lane] = f2bf(hx * dn) | (f2bf(hy * dn) << 16);
  } else if (EPI == 2) {
    outB[(size_t)wave * 64 + lane] = f2bf(ox) | (f2bf(oy) << 16);
  } else {
    ((float2*)outF)[(size_t)wave * 64 + lane] = make_float2(ox, oy);
  }
}

// ------------- W -> bf16 preconvert (3 x 128x128) ---------------------------

__global__ __launch_bounds__(256) void k_wcvt(const float* __restrict__ W0,
                                              const float* __restrict__ W1,
                                              const float* __restrict__ W2,
                                              unsigned short* __restrict__ out) {
  int i = blockIdx.x * 256 + threadIdx.x;
  if (i >= 3 * 16384) return;
  const float* W = (i < 16384) ? W0 : (i < 32768 ? W1 : W2);
  out[i] = (unsigned short)f2bf(W[i & 16383]);
}

// ------------- MFMA GEMM: C = X @ W^T, 16x16x32 bf16, no LDS ---------------
// Wave computes 16 rows x 128 cols. A frag: row=lane&15, k=(lane>>4)*8+j
// (16B contiguous). B frag: col=lane&15, same k pattern over W[col][k].
// C/D: col=lane&15, row=(lane>>4)*4+reg.
// BF16IN:  X is packed bf16 table; else f32 (cast inline).
// BF16OUT: Cb = bf16(acc * prescale[row]); else Cf = acc + bias[col].

template <bool BF16IN, bool BF16OUT>
__global__ __launch_bounds__(256) void k_gemm_mfma(const void* __restrict__ Xv,
                                                   const unsigned short* __restrict__ Wb,
                                                   const float* __restrict__ bias,
                                                   const float* __restrict__ prescale,
                                                   float* __restrict__ Cf,
                                                   unsigned short* __restrict__ Cb,
                                                   int nrows) {
  int wid  = threadIdx.x >> 6;
  int lane = threadIdx.x & 63;
  int r0   = blockIdx.x * 64 + wid * 16;
  int arow = r0 + (lane & 15);
  int kb   = (lane >> 4) * 8;
  bool rowok = arow < nrows;

  bf16x8 a[4];
  if (BF16IN) {
    const unsigned short* X = (const unsigned short*)Xv;
#pragma unroll
    for (int ks = 0; ks < 4; ++ks) {
      bf16x8 t;
      if (rowok) t = *reinterpret_cast<const bf16x8*>(X + (size_t)arow * D + ks * 32 + kb);
      else { for (int q = 0; q < 8; ++q) t[q] = 0; }
      a[ks] = t;
    }
  } else {
    const float* X = (const float*)Xv;
#pragma unroll
    for (int ks = 0; ks < 4; ++ks) {
      bf16x8 t;
      if (rowok) {
        const float* p = X + (size_t)arow * D + ks * 32 + kb;
        float4 f0 = *(const float4*)(p);
        float4 f1 = *(const float4*)(p + 4);
        t[0] = (short)f2bf(f0.x); t[1] = (short)f2bf(f0.y);
        t[2] = (short)f2bf(f0.z); t[3] = (short)f2bf(f0.w);
        t[4] = (short)f2bf(f1.x); t[5] = (short)f2bf(f1.y);
        t[6] = (short)f2bf(f1.z); t[7] = (short)f2bf(f1.w);
      } else {
        for (int q = 0; q < 8; ++q) t[q] = 0;
      }
      a[ks] = t;
    }
  }

  int rbase = r0 + (lane >> 4) * 4;
  float sc[4];
  if (BF16OUT) {
#pragma unroll
    for (int reg = 0; reg < 4; ++reg) {
      int rr = rbase + reg;
      sc[reg] = (prescale && rr < nrows) ? prescale[rr] : 1.0f;
    }
  }

#pragma unroll
  for (int ct = 0; ct < 8; ++ct) {
    int col = ct * 16 + (lane & 15);
    f32x4 acc = {0.f, 0.f, 0.f, 0.f};
#pragma unroll
    for (int ks = 0; ks < 4; ++ks) {
      bf16x8 b = *reinterpret_cast<const bf16x8*>(Wb + (size_t)col * D + ks * 32 + kb);
      acc = __builtin_amdgcn_mfma_f32_16x16x32_bf16(a[ks], b, acc, 0, 0, 0);
    }
    if (BF16OUT) {
#pragma unroll
      for (int reg = 0; reg < 4; ++reg) {
        int rr = rbase + reg;
        if (rr < nrows)
          Cb[(size_t)rr * D + col] = (unsigned short)f2bf(acc[reg] * sc[reg]);
      }
    } else {
      float bc = bias ? bias[col] : 0.f;
#pragma unroll
      for (int reg = 0; reg < 4; ++reg) {
        int rr = rbase + reg;
        if (rr < nrows) Cf[(size_t)rr * D + col] = acc[reg] + bc;
      }
    }
  }
}

// ---------------- f32 GEMM (fallback path only) ----------------

template <bool BF16OUT>
__global__ __launch_bounds__(256) void k_gemm128(const float* __restrict__ X,
                                                 const float* __restrict__ W,
                                                 const float* __restrict__ bias,
                                                 const float* __restrict__ prescale,
                                                 float* __restrict__ Cf,
                                                 unsigned short* __restrict__ Cb,
                                                 int nrows) {
  __shared__ float Xs[64][132];
  __shared__ float Ws[32][128];

  int tid = threadIdx.x;
  int row0 = blockIdx.x * 64;

  for (int t = tid; t < 2048; t += 256) {
    int r = t >> 5;
    int c4 = (t & 31) << 2;
    int gr = row0 + r;
    float4 v = make_float4(0.f, 0.f, 0.f, 0.f);
    if (gr < nrows) v = *(const float4*)(X + (size_t)gr * D + c4);
    Xs[r][c4 + 0] = v.x; Xs[r][c4 + 1] = v.y;
    Xs[r][c4 + 2] = v.z; Xs[r][c4 + 3] = v.w;
  }

  float acc[4][8];
#pragma unroll
  for (int i = 0; i < 4; ++i)
#pragma unroll
    for (int j = 0; j < 8; ++j) acc[i][j] = 0.f;

  int ty = tid >> 4, tx = tid & 15;
  int r0 = ty << 2, c0 = tx << 3;

  for (int k0 = 0; k0 < 128; k0 += 32) {
    int j = tid >> 1;
    int kkb = (tid & 1) << 4;
    const float4* wp = (const float4*)(W + j * D + k0 + kkb);
    float4 wa = wp[0], wb = wp[1], wc = wp[2], wd = wp[3];

    __syncthreads();
    Ws[kkb +  0][j] = wa.x; Ws[kkb +  1][j] = wa.y; Ws[kkb +  2][j] = wa.z; Ws[kkb +  3][j] = wa.w;
    Ws[kkb +  4][j] = wb.x; Ws[kkb +  5][j] = wb.y; Ws[kkb +  6][j] = wb.z; Ws[kkb +  7][j] = wb.w;
    Ws[kkb +  8][j] = wc.x; Ws[kkb +  9][j] = wc.y; Ws[kkb + 10][j] = wc.z; Ws[kkb + 11][j] = wc.w;
    Ws[kkb + 12][j] = wd.x; Ws[kkb + 13][j] = wd.y; Ws[kkb + 14][j] = wd.z; Ws[kkb + 15][j] = wd.w;
    __syncthreads();

#pragma unroll
    for (int kk = 0; kk < 32; ++kk) {
      float xi[4];
      xi[0] = Xs[r0 + 0][k0 + kk];
      xi[1] = Xs[r0 + 1][k0 + kk];
      xi[2] = Xs[r0 + 2][k0 + kk];
      xi[3] = Xs[r0 + 3][k0 + kk];
      float4 wv0 = *(const float4*)(&Ws[kk][c0]);
      float4 wv1 = *(const float4*)(&Ws[kk][c0 + 4]);
      float wf[8] = {wv0.x, wv0.y, wv0.z, wv0.w, wv1.x, wv1.y, wv1.z, wv1.w};
#pragma unroll
      for (int i = 0; i < 4; ++i)
#pragma unroll
        for (int jj = 0; jj < 8; ++jj) acc[i][jj] += xi[i] * wf[jj];
    }
  }

  float4 bv0 = make_float4(0.f, 0.f, 0.f, 0.f);
  float4 bv1 = make_float4(0.f, 0.f, 0.f, 0.f);
  if (bias) {
    bv0 = *(const float4*)(bias + c0);
    bv1 = *(const float4*)(bias + c0 + 4);
  }

#pragma unroll
  for (int i = 0; i < 4; ++i) {
    int gr = row0 + r0 + i;
    if (gr < nrows) {
      float o[8];
      o[0] = acc[i][0] + bv0.x; o[1] = acc[i][1] + bv0.y;
      o[2] = acc[i][2] + bv0.z; o[3] = acc[i][3] + bv0.w;
      o[4] = acc[i][4] + bv1.x; o[5] = acc[i][5] + bv1.y;
      o[6] = acc[i][6] + bv1.z; o[7] = acc[i][7] + bv1.w;
      if (BF16OUT) {
        float dn = prescale ? prescale[gr] : 1.0f;
        uint4 pk;
        pk.x = f2bf(o[0] * dn) | (f2bf(o[1] * dn) << 16);
        pk.y = f2bf(o[2] * dn) | (f2bf(o[3] * dn) << 16);
        pk.z = f2bf(o[4] * dn) | (f2bf(o[5] * dn) << 16);
        pk.w = f2bf(o[6] * dn) | (f2bf(o[7] * dn) << 16);
        *(uint4*)(Cb + (size_t)gr * D + c0) = pk;
      } else {
        *(float4*)(Cf + (size_t)gr * D + c0)     = make_float4(o[0], o[1], o[2], o[3]);
        *(float4*)(Cf + (size_t)gr * D + c0 + 4) = make_float4(o[4], o[5], o[6], o[7]);
      }
    }
  }
}

// ---------------- atomic fallback helpers --------------------

__global__ __launch_bounds__(256) void k_deg_f(const int* __restrict__ dst,
                                               float* __restrict__ deg, int E) {
  int i = blockIdx.x * 256 + threadIdx.x;
  if (i < E) atomicAdd(&deg[dst[i]], 1.0f);
}

__global__ __launch_bounds__(256) void k_dinv_f(float* __restrict__ deg, int n) {
  int i = blockIdx.x * 256 + threadIdx.x;
  if (i < n) deg[i] = rsqrtf(deg[i] + 1.0f);
}

__global__ __launch_bounds__(256) void k_selfmul(const float* __restrict__ X,
                                                 const float* __restrict__ dinv,
                                                 float* __restrict__ out, int n) {
  int i = blockIdx.x * 256 + threadIdx.x;
  if (i >= n * 32) return;
  int r = i >> 5, c4 = (i & 31) << 2;
  float di = dinv[r];
  float s = di * di;
  float4 h = *(const float4*)(X + (size_t)r * D + c4);
  h.x *= s; h.y *= s; h.z *= s; h.w *= s;
  *(float4*)(out + (size_t)r * D + c4) = h;
}

__global__ __launch_bounds__(256) void k_relumask(float* __restrict__ h,
                                                  const float* __restrict__ mask, int n) {
  int i = blockIdx.x * 256 + threadIdx.x;
  if (i >= n * 32) return;
  float4 v = *(const float4*)(h + (size_t)i * 4);
  float4 m = *(const float4*)(mask + (size_t)i * 4);
  v.x = fmaxf(v.x * m.x, 0.f);
  v.y = fmaxf(v.y * m.y, 0.f);
  v.z = fmaxf(v.z * m.z, 0.f);
  v.w = fmaxf(v.w * m.w, 0.f);
  *(float4*)(h + (size_t)i * 4) = v;
}

__global__ __launch_bounds__(256) void k_aggatomic(const float* __restrict__ X,
                                                   const int* __restrict__ src,
                                                   const int* __restrict__ dst,
                                                   const float* __restrict__ dinv,
                                                   float* __restrict__ out, int E) {
  int gid = blockIdx.x * 256 + threadIdx.x;
  int wave = gid >> 6;
  int lane = threadIdx.x & 63;
  int nw = (gridDim.x * 256) >> 6;
  for (int e = wave; e < E; e += nw) {
    int s = src[e], d = dst[e];
    float nrm = dinv[s] * dinv[d];
    float2 v = ((const float2*)(X + (size_t)s * D))[lane];
    float* op = out + (size_t)d * D + lane * 2;
    atomicAdd(op, v.x * nrm);
    atomicAdd(op + 1, v.y * nrm);
  }
}

__global__ __launch_bounds__(256) void k_addbias(float* __restrict__ C,
                                                 const float* __restrict__ bias, int n) {
  int i = blockIdx.x * 256 + threadIdx.x;
  if (i >= n * 32) return;
  int c4 = (i & 31) << 2;
  float4 v = *(const float4*)(C + (size_t)i * 4);
  float4 b = *(const float4*)(bias + c4);
  v.x += b.x; v.y += b.y; v.z += b.z; v.w += b.w;
  *(float4*)(C + (size_t)i * 4) = v;
}

// ---------------- launch ----------------

extern "C" void kernel_launch(void* const* d_in, const int* in_sizes, int n_in,
                              void* d_out, int out_size, void* d_ws, size_t ws_size,
                              hipStream_t stream) {
  const float* x    = (const float*)d_in[0];
  const int*   ei   = (const int*)d_in[1];
  const float* mask = (const float*)d_in[2];
  const float* W0   = (const float*)d_in[3];
  const float* b0   = (const float*)d_in[4];
  const float* W1   = (const float*)d_in[5];
  const float* b1   = (const float*)d_in[6];
  const float* W2   = (const float*)d_in[7];
  const float* b2   = (const float*)d_in[8];

  const int N = in_sizes[0] / D;
  const int E = in_sizes[1] / 2;
  const int* srcv = ei;
  const int* dstv = ei + E;

  float* out  = (float*)d_out;
  float* outA = out;                    // x_
  float* outB = out + (size_t)N * D;    // x2

  const size_t featBytes  = (size_t)N * D * sizeof(float);
  const size_t featBytesH = (size_t)N * D * sizeof(short);
  const int gGemm  = (N + 63) / 64;
  const int gEdge  = (E + 255) / 256;
  const int gNode  = (N + 255) / 256;
  const int gWaveN = (N + 3) / 4;
  const int gElem  = (N * 32 + 255) / 256;
  const int nb     = (N + BK_NODES - 1) >> BK_SHIFT;
  const int gBA    = (E + TILE_A - 1) / TILE_A;
  const int gCH    = (E + TILE_CH - 1) / TILE_CH;

  auto align256 = [](size_t v) { return (v + 255) & ~(size_t)255; };
  char* w = (char*)d_ws;
  size_t off = 0;
  int*   coarse    = (int*)(w + off);   off = align256(off + (NBMAX + 1) * 4);
  int*   cbase     = (int*)(w + off);   off = align256(off + (NBMAX + 1) * 4);
  int*   bCursor   = (int*)(w + off);   off = align256(off + NBMAX * 4);
  int*   rowptr    = (int*)(w + off);   off = align256(off + ((size_t)N + 1) * 4);
  float* dinv      = (float*)(w + off); off = align256(off + (size_t)N * 4);
  int*   srcSorted = (int*)(w + off);   off = align256(off + (size_t)E * 4);
  unsigned short* Wb = (unsigned short*)(w + off); off = align256(off + 3 * 16384 * 2);
  unsigned* h0bf   = (unsigned*)(w + off); off = align256(off + featBytesH);
  unsigned* hbf    = (unsigned*)(w + off); off = align256(off + featBytesH);
  unsigned* gbf    = (unsigned*)(w + off); off = align256(off + featBytesH);
  int*   packed    = (int*)gbf;         // aliases gbf (consumed before gbf written)
  size_t need = off;

  if (ws_size >= need && N <= 65536 && nb <= NBMAX &&
      (size_t)E * sizeof(int) <= featBytesH) {
    // ---- CSR build (3 kernels + tiny memset) ----
    hipMemsetAsync(coarse, 0, (size_t)(nb + 1) * sizeof(int), stream);
    k_chist<<<gCH, 256, 0, stream>>>(dstv, coarse, E, nb);
    k_cscan<<<1, NBMAX, 0, stream>>>(coarse, cbase, bCursor, nb, E);
    k_bucketA<<<gBA, 256, 0, stream>>>(srcv, dstv, bCursor, packed, E, nb);
    k_bucketB2<<<nb, 512, 0, stream>>>(packed, cbase, srcSorted, rowptr,
                                       dinv, N, E);
    // weights -> bf16 (W0 | W1 | W2 at Wb, Wb+16384, Wb+32768)
    k_wcvt<<<192, 256, 0, stream>>>(W0, W1, W2, Wb);

    // t0 = bf16(dinv * (x @ W0^T))
    k_gemm_mfma<false, true><<<gGemm, 256, 0, stream>>>(
        x, Wb, nullptr, dinv, nullptr, (unsigned short*)h0bf, N);
    // t1 = bf16(dinv * relu((agg + b0) * mask))
    k_aggb<1><<<gWaveN, 256, 0, stream>>>(h0bf, srcSorted, rowptr, dinv,
                                          b0, mask, nullptr, hbf, N);
    // g = bf16(agg)
    k_aggb<2><<<gWaveN, 256, 0, stream>>>(hbf, srcSorted, rowptr, dinv,
                                          nullptr, nullptr, nullptr, gbf, N);
    // x_ = g @ W1^T + b1 ; x2 = g @ W2^T + b2
    k_gemm_mfma<true, false><<<gGemm, 256, 0, stream>>>(
        gbf, Wb + 16384, b1, nullptr, outA, nullptr, N);
    k_gemm_mfma<true, false><<<gGemm, 256, 0, stream>>>(
        gbf, Wb + 32768, b2, nullptr, outB, nullptr, N);
  } else {
    // ---- atomic fallback (commuted, 2 aggs, all f32) ----
    float* fdinv = (float*)(w);
    float* fA    = (float*)(w + 0x40000);
    float* fB    = (float*)((char*)fA + featBytes);
    hipMemsetAsync(fdinv, 0, (size_t)N * sizeof(float), stream);
    k_deg_f<<<gEdge, 256, 0, stream>>>(dstv, fdinv, E);
    k_dinv_f<<<gNode, 256, 0, stream>>>(fdinv, N);
    k_gemm128<false><<<gGemm, 256, 0, stream>>>(x, W0, nullptr, nullptr, fB, nullptr, N);
    k_selfmul<<<gElem, 256, 0, stream>>>(fB, fdinv, fA, N);
    k_aggatomic<<<4096, 256, 0, stream>>>(fB, srcv, dstv, fdinv, fA, E);
    k_addbias<<<gElem, 256, 0, stream>>>(fA, b0, N);
    k_relumask<<<gElem, 256, 0, stream>>>(fA, mask, N);
    k_selfmul<<<gElem, 256, 0, stream>>>(fA, fdinv, fB, N);
    k_aggatomic<<<4096, 256, 0, stream>>>(fA, srcv, dstv, fdinv, fB, E);
    k_gemm128<false><<<gGemm, 256, 0, stream>>>(fB, W1, b1, nullptr, outA, nullptr, N);
    k_gemm128<false><<<gGemm, 256, 0, stream>>>(fB, W2, b2, nullptr, outB, nullptr, N);
  }
}

// Round 10
// 235.230 us; speedup vs baseline: 17.6140x; 1.0480x over previous
//
#include <hip/hip_runtime.h>

// ---------------------------------------------------------------------------
// GCN encoder, N=50000, E=1.6M, D=128.
// Round 10: agg unroll-16 + byte-offset srcSorted (latency hiding);
// fused dual MFMA GEMM for layers 1+2; bucketA caches edges in LDS pass1.
// ---------------------------------------------------------------------------

#define D 128
#define BK_SHIFT 7            // 128 nodes per bucket
#define BK_NODES 128
#define NBMAX 512             // max buckets (N <= 65536); also cscan width
#define BUFCAP 6144           // LDS staging capacity (edges) in k_bucketB2
#define TILE_A 2048           // edges per block in k_bucketA
#define TILE_CH 4096          // edges per block in k_chist

typedef __attribute__((ext_vector_type(8))) short bf16x8;
typedef __attribute__((ext_vector_type(4))) float f32x4;

static __device__ __forceinline__ unsigned f2bf(float f) {
  union { float f; unsigned u; } v; v.f = f;
  unsigned r = v.u + 0x7FFF + ((v.u >> 16) & 1);   // round to nearest even
  return r >> 16;
}
static __device__ __forceinline__ float bflo(unsigned u) {
  return __uint_as_float(u << 16);
}
static __device__ __forceinline__ float bfhi(unsigned u) {
  return __uint_as_float(u & 0xFFFF0000u);
}

// ---------------- CSR build ----------------

__global__ __launch_bounds__(256) void k_chist(const int* __restrict__ dst,
                                               int* __restrict__ coarse,
                                               int E, int nb) {
  __shared__ int bins[NBMAX];
  int t = threadIdx.x;
  int e0 = blockIdx.x * TILE_CH;
  for (int b = t; b < nb; b += 256) bins[b] = 0;
  __syncthreads();
  for (int i = t; i < TILE_CH; i += 256) {
    int e = e0 + i;
    if (e < E) atomicAdd(&bins[dst[e] >> BK_SHIFT], 1);
  }
  __syncthreads();
  for (int b = t; b < nb; b += 256) {
    int v = bins[b];
    if (v) atomicAdd(&coarse[b], v);
  }
}

__global__ __launch_bounds__(NBMAX) void k_cscan(const int* __restrict__ coarse,
                                                 int* __restrict__ cbase,
                                                 int* __restrict__ bCursor,
                                                 int nb, int E) {
  __shared__ int sm[NBMAX];
  int t = threadIdx.x;
  int v = (t < nb) ? coarse[t] : 0;
  sm[t] = v;
  __syncthreads();
  for (int off = 1; off < NBMAX; off <<= 1) {
    int y = (t >= off) ? sm[t - off] : 0;
    __syncthreads();
    sm[t] += y;
    __syncthreads();
  }
  int excl = sm[t] - v;
  if (t < nb) { cbase[t] = excl; bCursor[t] = excl; }
  if (t == 0) cbase[nb] = E;
}

// Phase A: bucket edges; pass1 caches packed edge words in LDS so globals
// are read exactly once. pv = src | dstoff<<16 | bkt<<23 (nb<=512 -> 9 bits).
__global__ __launch_bounds__(256) void k_bucketA(const int* __restrict__ src,
                                                 const int* __restrict__ dst,
                                                 int* __restrict__ bCursor,
                                                 int* __restrict__ packed,
                                                 int E, int nb) {
  __shared__ int hist[NBMAX];
  __shared__ int base[NBMAX];
  __shared__ unsigned pv[TILE_A];
  int t = threadIdx.x;
  int e0 = blockIdx.x * TILE_A;

  for (int b = t; b < nb; b += 256) hist[b] = 0;
  __syncthreads();

  for (int i = t; i < TILE_A; i += 256) {
    int e = e0 + i;
    if (e < E) {
      int d = dst[e];
      int s = src[e];
      unsigned bkt = (unsigned)d >> BK_SHIFT;
      pv[i] = (unsigned)(s & 0xFFFF) | ((unsigned)(d & (BK_NODES - 1)) << 16) |
              (bkt << 23);
      atomicAdd(&hist[bkt], 1);
    }
  }
  __syncthreads();

  for (int b = t; b < nb; b += 256) {
    int h = hist[b];
    if (h) base[b] = atomicAdd(&bCursor[b], h);
  }
  __syncthreads();

  for (int i = t; i < TILE_A; i += 256) {
    int e = e0 + i;
    if (e < E) {
      unsigned v = pv[i];
      unsigned bkt = v >> 23;
      int pos = atomicAdd(&base[bkt], 1);
      packed[pos] = (int)(v & 0x7FFFFF);
    }
  }
}

// Phase B: per bucket, node-level LDS histogram -> rowptr + dinv + sorted
// srcs (emitted as BYTE OFFSETS s<<8 into the 256B/row bf16 table).
__global__ __launch_bounds__(512) void k_bucketB2(const int* __restrict__ packed,
                                                  const int* __restrict__ cbase,
                                                  int* __restrict__ srcSorted,
                                                  int* __restrict__ rowptr,
                                                  float* __restrict__ dinv,
                                                  int n, int E) {
  __shared__ int histC[BK_NODES];
  __shared__ int cur[BK_NODES];
  __shared__ int buf[BUFCAP];
  int t = threadIdx.x;
  int bkt = blockIdx.x;
  int n0 = bkt << BK_SHIFT;
  int beg = cbase[bkt], end = cbase[bkt + 1];
  int cnt = end - beg;

  if (t < BK_NODES) histC[t] = 0;
  __syncthreads();

  for (int i = t; i < cnt; i += 512)
    atomicAdd(&histC[packed[beg + i] >> 16], 1);
  __syncthreads();

  if (t == 0) {
    int run = 0;
#pragma unroll
    for (int j = 0; j < BK_NODES; ++j) { cur[j] = run; run += histC[j]; }
  }
  __syncthreads();

  if (t < BK_NODES && n0 + t < n) {
    rowptr[n0 + t] = beg + cur[t];
    dinv[n0 + t]   = rsqrtf((float)histC[t] + 1.0f);
  }
  if (bkt == (int)gridDim.x - 1 && t == 0) rowptr[n] = E;
  __syncthreads();

  if (cnt <= BUFCAP) {
    for (int i = t; i < cnt; i += 512) {
      int p = packed[beg + i];
      int pos = atomicAdd(&cur[p >> 16], 1);
      buf[pos] = p & 0xFFFF;
    }
    __syncthreads();
    for (int i = t; i < cnt; i += 512)
      srcSorted[beg + i] = buf[i] << 8;           // byte offset
  } else {
    for (int i = t; i < cnt; i += 512) {
      int p = packed[beg + i];
      int pos = atomicAdd(&cur[p >> 16], 1);
      srcSorted[beg + pos] = (p & 0xFFFF) << 8;   // byte offset
    }
  }
}

// ------------- aggregation (wave/node; pre-scaled bf16 table) ---------------
// T[s] = bf16(dinv[s]*h[s]) packed 2/word; srcSorted holds byte offsets s<<8.
// ox = dinv[d]*(T[d] + sum T[s]).
// EPI=0: outF = f32.  EPI=1: h=relu((ox+bias)*mask); outB = bf16(dinv*h).
// EPI=2: outB = bf16(ox).

template <int EPI>
__global__ __launch_bounds__(256) void k_aggb(const unsigned* __restrict__ T,
                                              const int* __restrict__ srcSorted,
                                              const int* __restrict__ rowptr,
                                              const float* __restrict__ dinv,
                                              const float* __restrict__ bias,
                                              const float* __restrict__ mask,
                                              float* __restrict__ outF,
                                              unsigned* __restrict__ outB,
                                              int n) {
  int wave = (blockIdx.x * 256 + threadIdx.x) >> 6;
  int lane = threadIdx.x & 63;
  if (wave >= n) return;
  const char* Tb = (const char*)T;
  int lo = lane << 2;
  int beg = rowptr[wave], end = rowptr[wave + 1];
  float a0x = 0.f, a0y = 0.f, a1x = 0.f, a1y = 0.f;
  float a2x = 0.f, a2y = 0.f, a3x = 0.f, a3y = 0.f;
  int j = beg;
  for (; j + 15 < end; j += 16) {
    unsigned u[16];
#pragma unroll
    for (int q = 0; q < 16; ++q)
      u[q] = *(const unsigned*)(Tb + srcSorted[j + q] + lo);
#pragma unroll
    for (int q = 0; q < 16; q += 4) {
      a0x += bflo(u[q + 0]);  a0y += bfhi(u[q + 0]);
      a1x += bflo(u[q + 1]);  a1y += bfhi(u[q + 1]);
      a2x += bflo(u[q + 2]);  a2y += bfhi(u[q + 2]);
      a3x += bflo(u[q + 3]);  a3y += bfhi(u[q + 3]);
    }
  }
  for (; j + 7 < end; j += 8) {
    unsigned u[8];
#pragma unroll
    for (int q = 0; q < 8; ++q)
      u[q] = *(const unsigned*)(Tb + srcSorted[j + q] + lo);
#pragma unroll
    for (int q = 0; q < 8; q += 4) {
      a0x += bflo(u[q + 0]);  a0y += bfhi(u[q + 0]);
      a1x += bflo(u[q + 1]);  a1y += bfhi(u[q + 1]);
      a2x += bflo(u[q + 2]);  a2y += bfhi(u[q + 2]);
      a3x += bflo(u[q + 3]);  a3y += bfhi(u[q + 3]);
    }
  }
  for (; j < end; ++j) {
    unsigned u = *(const unsigned*)(Tb + srcSorted[j] + lo);
    a0x += bflo(u);
    a0y += bfhi(u);
  }
  unsigned us = T[(size_t)wave * 64 + lane];   // self term
  float dn = dinv[wave];
  float ox = ((a0x + a1x) + (a2x + a3x) + bflo(us)) * dn;
  float oy = ((a0y + a1y) + (a2y + a3y) + bfhi(us)) * dn;
  if (EPI == 1) {
    float2 bv = ((const float2*)bias)[lane];
    float2 mv = ((const float2*)mask)[(size_t)wave * 64 + lane];
    float hx = fmaxf((ox + bv.x) * mv.x, 0.f);
    float hy = fmaxf((oy + bv.y) * mv.y, 0.f);
    outB[(size_t)wave * 64 + lane] = f2bf(hx * dn) | (f2bf(hy * dn) << 16);
  } else if (EPI == 2) {
    outB[(size_t)wave * 64 + lane] = f2bf(ox) | (f2bf(oy) << 16);
  } else {
    ((float2*)outF)[(size_t)wave * 64 + lane] = make_float2(ox, oy);
  }
}

// ------------- W -> bf16 preconvert (3 x 128x128) ---------------------------

__global__ __launch_bounds__(256) void k_wcvt(const float* __restrict__ W0,
                                              const float* __restrict__ W1,
                                              const float* __restrict__ W2,
                                              unsigned short* __restrict__ out) {
  int i = blockIdx.x * 256 + threadIdx.x;
  if (i >= 3 * 16384) return;
  const float* W = (i < 16384) ? W0 : (i < 32768 ? W1 : W2);
  out[i] = (unsigned short)f2bf(W[i & 16383]);
}

// ------------- MFMA GEMM: C = X @ W^T, 16x16x32 bf16, no LDS ---------------
// Wave computes 16 rows x 128 cols. A frag: row=lane&15, k=(lane>>4)*8+j.
// B frag: col=lane&15, same k over W[col][k]. C/D: col=lane&15,
// row=(lane>>4)*4+reg.

template <bool BF16IN, bool BF16OUT>
__global__ __launch_bounds__(256) void k_gemm_mfma(const void* __restrict__ Xv,
                                                   const unsigned short* __restrict__ Wb,
                                                   const float* __restrict__ bias,
                                                   const float* __restrict__ prescale,
                                                   float* __restrict__ Cf,
                                                   unsigned short* __restrict__ Cb,
                                                   int nrows) {
  int wid  = threadIdx.x >> 6;
  int lane = threadIdx.x & 63;
  int r0   = blockIdx.x * 64 + wid * 16;
  int arow = r0 + (lane & 15);
  int kb   = (lane >> 4) * 8;
  bool rowok = arow < nrows;

  bf16x8 a[4];
  if (BF16IN) {
    const unsigned short* X = (const unsigned short*)Xv;
#pragma unroll
    for (int ks = 0; ks < 4; ++ks) {
      bf16x8 t;
      if (rowok) t = *reinterpret_cast<const bf16x8*>(X + (size_t)arow * D + ks * 32 + kb);
      else { for (int q = 0; q < 8; ++q) t[q] = 0; }
      a[ks] = t;
    }
  } else {
    const float* X = (const float*)Xv;
#pragma unroll
    for (int ks = 0; ks < 4; ++ks) {
      bf16x8 t;
      if (rowok) {
        const float* p = X + (size_t)arow * D + ks * 32 + kb;
        float4 f0 = *(const float4*)(p);
        float4 f1 = *(const float4*)(p + 4);
        t[0] = (short)f2bf(f0.x); t[1] = (short)f2bf(f0.y);
        t[2] = (short)f2bf(f0.z); t[3] = (short)f2bf(f0.w);
        t[4] = (short)f2bf(f1.x); t[5] = (short)f2bf(f1.y);
        t[6] = (short)f2bf(f1.z); t[7] = (short)f2bf(f1.w);
      } else {
        for (int q = 0; q < 8; ++q) t[q] = 0;
      }
      a[ks] = t;
    }
  }

  int rbase = r0 + (lane >> 4) * 4;
  float sc[4];
  if (BF16OUT) {
#pragma unroll
    for (int reg = 0; reg < 4; ++reg) {
      int rr = rbase + reg;
      sc[reg] = (prescale && rr < nrows) ? prescale[rr] : 1.0f;
    }
  }

#pragma unroll
  for (int ct = 0; ct < 8; ++ct) {
    int col = ct * 16 + (lane & 15);
    f32x4 acc = {0.f, 0.f, 0.f, 0.f};
#pragma unroll
    for (int ks = 0; ks < 4; ++ks) {
      bf16x8 b = *reinterpret_cast<const bf16x8*>(Wb + (size_t)col * D + ks * 32 + kb);
      acc = __builtin_amdgcn_mfma_f32_16x16x32_bf16(a[ks], b, acc, 0, 0, 0);
    }
    if (BF16OUT) {
#pragma unroll
      for (int reg = 0; reg < 4; ++reg) {
        int rr = rbase + reg;
        if (rr < nrows)
          Cb[(size_t)rr * D + col] = (unsigned short)f2bf(acc[reg] * sc[reg]);
      }
    } else {
      float bc = bias ? bias[col] : 0.f;
#pragma unroll
      for (int reg = 0; reg < 4; ++reg) {
        int rr = rbase + reg;
        if (rr < nrows) Cf[(size_t)rr * D + col] = acc[reg] + bc;
      }
    }
  }
}

// Fused dual GEMM: C1 = X@W1^T + b1, C2 = X@W2^T + b2 (bf16 in, f32 out).
// A fragments loaded once, reused for both weight matrices.
__global__ __launch_bounds__(256) void k_gemm_mfma2(const unsigned short* __restrict__ X,
                                                    const unsigned short* __restrict__ W1b,
                                                    const unsigned short* __restrict__ W2b,
                                                    const float* __restrict__ b1,
                                                    const float* __restrict__ b2,
                                                    float* __restrict__ C1,
                                                    float* __restrict__ C2,
                                                    int nrows) {
  int wid  = threadIdx.x >> 6;
  int lane = threadIdx.x & 63;
  int r0   = blockIdx.x * 64 + wid * 16;
  int arow = r0 + (lane & 15);
  int kb   = (lane >> 4) * 8;
  bool rowok = arow < nrows;

  bf16x8 a[4];
#pragma unroll
  for (int ks = 0; ks < 4; ++ks) {
    bf16x8 t;
    if (rowok) t = *reinterpret_cast<const bf16x8*>(X + (size_t)arow * D + ks * 32 + kb);
    else { for (int q = 0; q < 8; ++q) t[q] = 0; }
    a[ks] = t;
  }

  int rbase = r0 + (lane >> 4) * 4;

#pragma unroll
  for (int wm = 0; wm < 2; ++wm) {
    const unsigned short* Wb = (wm == 0) ? W1b : W2b;
    const float* bias        = (wm == 0) ? b1 : b2;
    float* Cf                = (wm == 0) ? C1 : C2;
#pragma unroll
    for (int ct = 0; ct < 8; ++ct) {
      int col = ct * 16 + (lane & 15);
      f32x4 acc = {0.f, 0.f, 0.f, 0.f};
#pragma unroll
      for (int ks = 0; ks < 4; ++ks) {
        bf16x8 b = *reinterpret_cast<const bf16x8*>(Wb + (size_t)col * D + ks * 32 + kb);
        acc = __builtin_amdgcn_mfma_f32_16x16x32_bf16(a[ks], b, acc, 0, 0, 0);
      }
      float bc = bias[col];
#pragma unroll
      for (int reg = 0; reg < 4; ++reg) {
        int rr = rbase + reg;
        if (rr < nrows) Cf[(size_t)rr * D + col] = acc[reg] + bc;
      }
    }
  }
}

// ---------------- f32 GEMM (fallback path only) ----------------

template <bool BF16OUT>
__global__ __launch_bounds__(256) void k_gemm128(const float* __restrict__ X,
                                                 const float* __restrict__ W,
                                                 const float* __restrict__ bias,
                                                 const float* __restrict__ prescale,
                                                 float* __restrict__ Cf,
                                                 unsigned short* __restrict__ Cb,
                                                 int nrows) {
  __shared__ float Xs[64][132];
  __shared__ float Ws[32][128];

  int tid = threadIdx.x;
  int row0 = blockIdx.x * 64;

  for (int t = tid; t < 2048; t += 256) {
    int r = t >> 5;
    int c4 = (t & 31) << 2;
    int gr = row0 + r;
    float4 v = make_float4(0.f, 0.f, 0.f, 0.f);
    if (gr < nrows) v = *(const float4*)(X + (size_t)gr * D + c4);
    Xs[r][c4 + 0] = v.x; Xs[r][c4 + 1] = v.y;
    Xs[r][c4 + 2] = v.z; Xs[r][c4 + 3] = v.w;
  }

  float acc[4][8];
#pragma unroll
  for (int i = 0; i < 4; ++i)
#pragma unroll
    for (int j = 0; j < 8; ++j) acc[i][j] = 0.f;

  int ty = tid >> 4, tx = tid & 15;
  int r0 = ty << 2, c0 = tx << 3;

  for (int k0 = 0; k0 < 128; k0 += 32) {
    int j = tid >> 1;
    int kkb = (tid & 1) << 4;
    const float4* wp = (const float4*)(W + j * D + k0 + kkb);
    float4 wa = wp[0], wb = wp[1], wc = wp[2], wd = wp[3];

    __syncthreads();
    Ws[kkb +  0][j] = wa.x; Ws[kkb +  1][j] = wa.y; Ws[kkb +  2][j] = wa.z; Ws[kkb +  3][j] = wa.w;
    Ws[kkb +  4][j] = wb.x; Ws[kkb +  5][j] = wb.y; Ws[kkb +  6][j] = wb.z; Ws[kkb +  7][j] = wb.w;
    Ws[kkb +  8][j] = wc.x; Ws[kkb +  9][j] = wc.y; Ws[kkb + 10][j] = wc.z; Ws[kkb + 11][j] = wc.w;
    Ws[kkb + 12][j] = wd.x; Ws[kkb + 13][j] = wd.y; Ws[kkb + 14][j] = wd.z; Ws[kkb + 15][j] = wd.w;
    __syncthreads();

#pragma unroll
    for (int kk = 0; kk < 32; ++kk) {
      float xi[4];
      xi[0] = Xs[r0 + 0][k0 + kk];
      xi[1] = Xs[r0 + 1][k0 + kk];
      xi[2] = Xs[r0 + 2][k0 + kk];
      xi[3] = Xs[r0 + 3][k0 + kk];
      float4 wv0 = *(const float4*)(&Ws[kk][c0]);
      float4 wv1 = *(const float4*)(&Ws[kk][c0 + 4]);
      float wf[8] = {wv0.x, wv0.y, wv0.z, wv0.w, wv1.x, wv1.y, wv1.z, wv1.w};
#pragma unroll
      for (int i = 0; i < 4; ++i)
#pragma unroll
        for (int jj = 0; jj < 8; ++jj) acc[i][jj] += xi[i] * wf[jj];
    }
  }

  float4 bv0 = make_float4(0.f, 0.f, 0.f, 0.f);
  float4 bv1 = make_float4(0.f, 0.f, 0.f, 0.f);
  if (bias) {
    bv0 = *(const float4*)(bias + c0);
    bv1 = *(const float4*)(bias + c0 + 4);
  }

#pragma unroll
  for (int i = 0; i < 4; ++i) {
    int gr = row0 + r0 + i;
    if (gr < nrows) {
      float o[8];
      o[0] = acc[i][0] + bv0.x; o[1] = acc[i][1] + bv0.y;
      o[2] = acc[i][2] + bv0.z; o[3] = acc[i][3] + bv0.w;
      o[4] = acc[i][4] + bv1.x; o[5] = acc[i][5] + bv1.y;
      o[6] = acc[i][6] + bv1.z; o[7] = acc[i][7] + bv1.w;
      if (BF16OUT) {
        float dn = prescale ? prescale[gr] : 1.0f;
        uint4 pk;
        pk.x = f2bf(o[0] * dn) | (f2bf(o[1] * dn) << 16);
        pk.y = f2bf(o[2] * dn) | (f2bf(o[3] * dn) << 16);
        pk.z = f2bf(o[4] * dn) | (f2bf(o[5] * dn) << 16);
        pk.w = f2bf(o[6] * dn) | (f2bf(o[7] * dn) << 16);
        *(uint4*)(Cb + (size_t)gr * D + c0) = pk;
      } else {
        *(float4*)(Cf + (size_t)gr * D + c0)     = make_float4(o[0], o[1], o[2], o[3]);
        *(float4*)(Cf + (size_t)gr * D + c0 + 4) = make_float4(o[4], o[5], o[6], o[7]);
      }
    }
  }
}

// ---------------- atomic fallback helpers --------------------

__global__ __launch_bounds__(256) void k_deg_f(const int* __restrict__ dst,
                                               float* __restrict__ deg, int E) {
  int i = blockIdx.x * 256 + threadIdx.x;
  if (i < E) atomicAdd(&deg[dst[i]], 1.0f);
}

__global__ __launch_bounds__(256) void k_dinv_f(float* __restrict__ deg, int n) {
  int i = blockIdx.x * 256 + threadIdx.x;
  if (i < n) deg[i] = rsqrtf(deg[i] + 1.0f);
}

__global__ __launch_bounds__(256) void k_selfmul(const float* __restrict__ X,
                                                 const float* __restrict__ dinv,
                                                 float* __restrict__ out, int n) {
  int i = blockIdx.x * 256 + threadIdx.x;
  if (i >= n * 32) return;
  int r = i >> 5, c4 = (i & 31) << 2;
  float di = dinv[r];
  float s = di * di;
  float4 h = *(const float4*)(X + (size_t)r * D + c4);
  h.x *= s; h.y *= s; h.z *= s; h.w *= s;
  *(float4*)(out + (size_t)r * D + c4) = h;
}

__global__ __launch_bounds__(256) void k_relumask(float* __restrict__ h,
                                                  const float* __restrict__ mask, int n) {
  int i = blockIdx.x * 256 + threadIdx.x;
  if (i >= n * 32) return;
  float4 v = *(const float4*)(h + (size_t)i * 4);
  float4 m = *(const float4*)(mask + (size_t)i * 4);
  v.x = fmaxf(v.x * m.x, 0.f);
  v.y = fmaxf(v.y * m.y, 0.f);
  v.z = fmaxf(v.z * m.z, 0.f);
  v.w = fmaxf(v.w * m.w, 0.f);
  *(float4*)(h + (size_t)i * 4) = v;
}

__global__ __launch_bounds__(256) void k_aggatomic(const float* __restrict__ X,
                                                   const int* __restrict__ src,
                                                   const int* __restrict__ dst,
                                                   const float* __restrict__ dinv,
                                                   float* __restrict__ out, int E) {
  int gid = blockIdx.x * 256 + threadIdx.x;
  int wave = gid >> 6;
  int lane = threadIdx.x & 63;
  int nw = (gridDim.x * 256) >> 6;
  for (int e = wave; e < E; e += nw) {
    int s = src[e], d = dst[e];
    float nrm = dinv[s] * dinv[d];
    float2 v = ((const float2*)(X + (size_t)s * D))[lane];
    float* op = out + (size_t)d * D + lane * 2;
    atomicAdd(op, v.x * nrm);
    atomicAdd(op + 1, v.y * nrm);
  }
}

__global__ __launch_bounds__(256) void k_addbias(float* __restrict__ C,
                                                 const float* __restrict__ bias, int n) {
  int i = blockIdx.x * 256 + threadIdx.x;
  if (i >= n * 32) return;
  int c4 = (i & 31) << 2;
  float4 v = *(const float4*)(C + (size_t)i * 4);
  float4 b = *(const float4*)(bias + c4);
  v.x += b.x; v.y += b.y; v.z += b.z; v.w += b.w;
  *(float4*)(C + (size_t)i * 4) = v;
}

// ---------------- launch ----------------

extern "C" void kernel_launch(void* const* d_in, const int* in_sizes, int n_in,
                              void* d_out, int out_size, void* d_ws, size_t ws_size,
                              hipStream_t stream) {
  const float* x    = (const float*)d_in[0];
  const int*   ei   = (const int*)d_in[1];
  const float* mask = (const float*)d_in[2];
  const float* W0   = (const float*)d_in[3];
  const float* b0   = (const float*)d_in[4];
  const float* W1   = (const float*)d_in[5];
  const float* b1   = (const float*)d_in[6];
  const float* W2   = (const float*)d_in[7];
  const float* b2   = (const float*)d_in[8];

  const int N = in_sizes[0] / D;
  const int E = in_sizes[1] / 2;
  const int* srcv = ei;
  const int* dstv = ei + E;

  float* out  = (float*)d_out;
  float* outA = out;                    // x_
  float* outB = out + (size_t)N * D;    // x2

  const size_t featBytes  = (size_t)N * D * sizeof(float);
  const size_t featBytesH = (size_t)N * D * sizeof(short);
  const int gGemm  = (N + 63) / 64;
  const int gEdge  = (E + 255) / 256;
  const int gNode  = (N + 255) / 256;
  const int gWaveN = (N + 3) / 4;
  const int gElem  = (N * 32 + 255) / 256;
  const int nb     = (N + BK_NODES - 1) >> BK_SHIFT;
  const int gBA    = (E + TILE_A - 1) / TILE_A;
  const int gCH    = (E + TILE_CH - 1) / TILE_CH;

  auto align256 = [](size_t v) { return (v + 255) & ~(size_t)255; };
  char* w = (char*)d_ws;
  size_t off = 0;
  int*   coarse    = (int*)(w + off);   off = align256(off + (NBMAX + 1) * 4);
  int*   cbase     = (int*)(w + off);   off = align256(off + (NBMAX + 1) * 4);
  int*   bCursor   = (int*)(w + off);   off = align256(off + NBMAX * 4);
  int*   rowptr    = (int*)(w + off);   off = align256(off + ((size_t)N + 1) * 4);
  float* dinv      = (float*)(w + off); off = align256(off + (size_t)N * 4);
  int*   srcSorted = (int*)(w + off);   off = align256(off + (size_t)E * 4);
  unsigned short* Wb = (unsigned short*)(w + off); off = align256(off + 3 * 16384 * 2);
  unsigned* h0bf   = (unsigned*)(w + off); off = align256(off + featBytesH);
  unsigned* hbf    = (unsigned*)(w + off); off = align256(off + featBytesH);
  unsigned* gbf    = (unsigned*)(w + off); off = align256(off + featBytesH);
  int*   packed    = (int*)gbf;         // aliases gbf (consumed before gbf written)
  size_t need = off;

  if (ws_size >= need && N <= 65536 && nb <= NBMAX &&
      (size_t)E * sizeof(int) <= featBytesH) {
    // ---- CSR build ----
    hipMemsetAsync(coarse, 0, (size_t)(nb + 1) * sizeof(int), stream);
    k_chist<<<gCH, 256, 0, stream>>>(dstv, coarse, E, nb);
    k_cscan<<<1, NBMAX, 0, stream>>>(coarse, cbase, bCursor, nb, E);
    k_bucketA<<<gBA, 256, 0, stream>>>(srcv, dstv, bCursor, packed, E, nb);
    k_bucketB2<<<nb, 512, 0, stream>>>(packed, cbase, srcSorted, rowptr,
                                       dinv, N, E);
    // weights -> bf16 (W0 | W1 | W2 at Wb, Wb+16384, Wb+32768)
    k_wcvt<<<192, 256, 0, stream>>>(W0, W1, W2, Wb);

    // t0 = bf16(dinv * (x @ W0^T))
    k_gemm_mfma<false, true><<<gGemm, 256, 0, stream>>>(
        x, Wb, nullptr, dinv, nullptr, (unsigned short*)h0bf, N);
    // t1 = bf16(dinv * relu((agg + b0) * mask))
    k_aggb<1><<<gWaveN, 256, 0, stream>>>(h0bf, srcSorted, rowptr, dinv,
                                          b0, mask, nullptr, hbf, N);
    // g = bf16(agg)
    k_aggb<2><<<gWaveN, 256, 0, stream>>>(hbf, srcSorted, rowptr, dinv,
                                          nullptr, nullptr, nullptr, gbf, N);
    // x_ = g @ W1^T + b1 ; x2 = g @ W2^T + b2 (fused)
    k_gemm_mfma2<<<gGemm, 256, 0, stream>>>(
        (const unsigned short*)gbf, Wb + 16384, Wb + 32768, b1, b2,
        outA, outB, N);
  } else {
    // ---- atomic fallback (commuted, 2 aggs, all f32) ----
    float* fdinv = (float*)(w);
    float* fA    = (float*)(w + 0x40000);
    float* fB    = (float*)((char*)fA + featBytes);
    hipMemsetAsync(fdinv, 0, (size_t)N * sizeof(float), stream);
    k_deg_f<<<gEdge, 256, 0, stream>>>(dstv, fdinv, E);
    k_dinv_f<<<gNode, 256, 0, stream>>>(fdinv, N);
    k_gemm128<false><<<gGemm, 256, 0, stream>>>(x, W0, nullptr, nullptr, fB, nullptr, N);
    k_selfmul<<<gElem, 256, 0, stream>>>(fB, fdinv, fA, N);
    k_aggatomic<<<4096, 256, 0, stream>>>(fB, srcv, dstv, fdinv, fA, E);
    k_addbias<<<gElem, 256, 0, stream>>>(fA, b0, N);
    k_relumask<<<gElem, 256, 0, stream>>>(fA, mask, N);
    k_selfmul<<<gElem, 256, 0, stream>>>(fA, fdinv, fB, N);
    k_aggatomic<<<4096, 256, 0, stream>>>(fA, srcv, dstv, fdinv, fB, E);
    k_gemm128<false><<<gGemm, 256, 0, stream>>>(fB, W1, b1, nullptr, outA, nullptr, N);
    k_gemm128<false><<<gGemm, 256, 0, stream>>>(fB, W2, b2, nullptr, outB, nullptr, N);
  }
}